// Round 17
// baseline (314.841 us; speedup 1.0000x reference)
//
#include <hip/hip_runtime.h>
#include <hip/hip_bf16.h>
#include <hip/hip_fp8.h>

constexpr int Cc  = 256;
constexpr int NQ  = 100;
constexpr int Bb  = 8;
constexpr int HW  = 64 * 64;
constexpr int G49 = 49;

typedef __bf16 bf16x8 __attribute__((ext_vector_type(8)));
typedef float  f32x4  __attribute__((ext_vector_type(4)));

__device__ __forceinline__ float ldbf(const __hip_bfloat16* p) { return __bfloat162float(*p); }

__device__ __forceinline__ unsigned pk2(float a, float b) {
    union { unsigned u; __bf16 h[2]; } x;
    x.h[0] = (__bf16)a; x.h[1] = (__bf16)b;
    return x.u;
}
__device__ __forceinline__ float upk(unsigned u, int k) {
    union { unsigned u2; __bf16 h[2]; } x; x.u2 = u;
    return (float)x.h[k];
}
__device__ __forceinline__ float fp8lo(unsigned v) {
    union { unsigned char c; __hip_fp8_e4m3 f; } u; u.c = (unsigned char)(v & 255);
    return (float)u.f;
}
__device__ __forceinline__ float fp8hi(unsigned v) {
    union { unsigned char c; __hip_fp8_e4m3 f; } u; u.c = (unsigned char)((v >> 8) & 255);
    return (float)u.f;
}

// swizzled bf16 LDS write: buffer [64 rows][256 cols] bf16, row stride 512B,
// byte ^= (row&7)<<4 (T2 swizzle)
__device__ __forceinline__ void lwb16(char* buf, int row, int col, float v) {
    int byte = (row * 512 + col * 2) ^ ((row & 7) << 4);
    *(__bf16*)(buf + byte) = (__bf16)v;
}

// ---------------------------------------------------------------------------
// prep1 (unchanged): qk1, qf1, geW1, gef1
// ---------------------------------------------------------------------------
__global__ void prep1_kernel(const float* __restrict__ q, const float* __restrict__ qpe,
                             const float* __restrict__ ge,
                             const float* __restrict__ Wq, const float* __restrict__ bq,
                             const float* __restrict__ W1l, const float* __restrict__ b1l,
                             const float* __restrict__ f1_w1, const float* __restrict__ f1_b1,
                             __hip_bfloat16* __restrict__ qk1, __hip_bfloat16* __restrict__ qf1,
                             __hip_bfloat16* __restrict__ geW1, __hip_bfloat16* __restrict__ gef1)
{
    __shared__ float s[Cc];
    __shared__ float rq[Cc];
    __shared__ float qqs[Cc];
    const int t = threadIdx.x;
    const int blk = blockIdx.x;
    if (blk < Bb * NQ) {
        float a = q[blk * Cc + t], p = qpe[blk * Cc + t];
        rq[t] = a; s[t] = a + p;
        __syncthreads();
        float acc1 = bq[t], acc2 = f1_b1[t];
        for (int k = 0; k < Cc; k++) {
            acc1 = fmaf(s[k],  Wq[k * Cc + t],    acc1);
            acc2 = fmaf(rq[k], f1_w1[k * Cc + t], acc2);
        }
        qqs[t] = acc1;
        qf1[blk * Cc + t] = __float2bfloat16(acc2);
        __syncthreads();
        float acc3 = b1l[t];
        for (int k = 0; k < Cc; k++) acc3 = fmaf(qqs[k], W1l[k * Cc + t], acc3);
        qk1[blk * Cc + t] = __float2bfloat16(acc3);
    } else {
        int g = blk - Bb * NQ;
        s[t] = ge[g * Cc + t];
        __syncthreads();
        float acc1 = 0.f, acc2 = 0.f;
        for (int k = 0; k < Cc; k++) {
            acc1 = fmaf(s[k], W1l[k * Cc + t],   acc1);
            acc2 = fmaf(s[k], f1_w1[k * Cc + t], acc2);
        }
        geW1[g * Cc + t] = __float2bfloat16(acc1);
        gef1[g * Cc + t] = __float2bfloat16(acc2);
    }
}

// ---------------------------------------------------------------------------
// wfold: W_zc = Wz @ W2l (f32) ; bzW2l = bz @ W2l
// ---------------------------------------------------------------------------
__global__ void wfold_kernel(const float* __restrict__ Wz, const float* __restrict__ W2l,
                             const float* __restrict__ bz,
                             float* __restrict__ Wzc, float* __restrict__ bzW2l)
{
    __shared__ float s[Cc];
    const int t = threadIdx.x;
    const int blk = blockIdx.x;
    if (blk < Cc) {
        s[t] = Wz[blk * Cc + t];
        __syncthreads();
        float a = 0.f;
        for (int d = 0; d < Cc; d++) a = fmaf(s[d], W2l[d * Cc + t], a);
        Wzc[blk * Cc + t] = a;
    } else {
        s[t] = bz[t];
        __syncthreads();
        float a = 0.f;
        for (int d = 0; d < Cc; d++) a = fmaf(s[d], W2l[d * Cc + t], a);
        bzW2l[t] = a;
    }
}

// ---------------------------------------------------------------------------
// wprep: W[k][n] f32 -> fragment-ordered bf16 WTf[m][w][nt][ks][lane][8]
// m: 0=Wzc 1=f2w1 (projA) | 2=g2w1 3=g2w2 4=f2w2 5=g1w1 6=g1w2 7=f1w2 8=outw
// ---------------------------------------------------------------------------
__global__ void wprep_kernel(const float* __restrict__ Wzc,  const float* __restrict__ f2w1,
                             const float* __restrict__ g2w1, const float* __restrict__ g2w2,
                             const float* __restrict__ f2w2, const float* __restrict__ g1w1,
                             const float* __restrict__ g1w2, const float* __restrict__ f1w2,
                             const float* __restrict__ outw,
                             __hip_bfloat16* __restrict__ WTf)
{
    __shared__ float ld[64][65];
    const float* srcs[9] = {Wzc, f2w1, g2w1, g2w2, f2w2, g1w1, g1w2, f1w2, outw};
    const int m  = blockIdx.z;
    const int w  = blockIdx.y;
    const int k0 = blockIdx.x * 64;
    const float* src = srcs[m];
    __hip_bfloat16* dst = WTf + (size_t)m * 65536;
    const int t = threadIdx.x;
    const int n0 = w * 64;
#pragma unroll
    for (int j = 0; j < 16; j++) {
        int idx = j * 256 + t; int r = idx >> 6, c = idx & 63;
        ld[r][c] = src[(size_t)(k0 + r) * Cc + n0 + c];
    }
    __syncthreads();
#pragma unroll
    for (int j = 0; j < 16; j++) {
        int idx = j * 256 + t;
        int e  = idx & 7;
        int l  = (idx >> 3) & 63;
        int kk = (idx >> 9) & 1;
        int nt = idx >> 10;
        int k_loc = kk * 32 + ((l >> 4) & 3) * 8 + e;
        int n_loc = nt * 16 + (l & 15);
        int oofs  = ((w * 4 + nt) * 8 + (k0 >> 5) + kk) * 512 + (idx & 511);
        dst[oofs] = __float2bfloat16(ld[k_loc][n_loc]);
    }
}

// ---------------------------------------------------------------------------
// 4-wave MFMA GEMM core (projA only)
// ---------------------------------------------------------------------------
__device__ __forceinline__ void run_gemm4(const char* __restrict__ Abuf,
                                          const __bf16* __restrict__ Wf,
                                          int l15, int lhi, int lane, int w, int n0, f32x4* acc)
{
#pragma unroll
    for (int j = 0; j < 16; j++) { f32x4 v = {0.f, 0.f, 0.f, 0.f}; acc[j] = v; }
#pragma unroll
    for (int ks = 0; ks < 8; ks++) {
        bf16x8 bfr[4], afr[4];
#pragma unroll
        for (int nt = 0; nt < 4; nt++)
            bfr[nt] = *(const bf16x8*)(Wf + ((((w * 4 + nt) * 8 + ks) * 64) + lane) * 8);
#pragma unroll
        for (int mt = 0; mt < 4; mt++) {
            int row = mt * 16 + l15;
            int byte = (row * 512 + (ks * 32 + lhi * 8) * 2) ^ ((row & 7) << 4);
            afr[mt] = *(const bf16x8*)(Abuf + byte);
        }
#pragma unroll
        for (int mt = 0; mt < 4; mt++)
#pragma unroll
            for (int nt = 0; nt < 4; nt++)
                acc[mt * 4 + nt] = __builtin_amdgcn_mfma_f32_16x16x32_bf16(
                    afr[mt], bfr[nt], acc[mt * 4 + nt], 0, 0, 0);
    }
}

// ---------------------------------------------------------------------------
// projA (unchanged): y1 = (feat+pe)@Wzc (fp8), y2 = feat@f2_w1 (bf16)
// ---------------------------------------------------------------------------
__global__ __launch_bounds__(256, 2) void projA_kernel(
    const float* __restrict__ feat, const float* __restrict__ feat_pe,
    const __hip_bfloat16* __restrict__ WTf,
    __hip_fp8_e4m3* __restrict__ y1, __hip_bfloat16* __restrict__ y2)
{
    extern __shared__ char smem[];
    char* bufA = smem;
    char* bufB = smem + 32768;

    const int t = threadIdx.x;
    const int lane = t & 63;
    const int w = t >> 6;
    const int n0 = w * 64;
    const int l15 = lane & 15, lhi = lane >> 4;
    const int b = blockIdx.x >> 6;
    const int pix0 = (blockIdx.x & 63) * 64;

    const float* fp = feat    + ((size_t)(b * Cc + t)) * HW + pix0;
    const float* pp = feat_pe + ((size_t)(b * Cc + t)) * HW + pix0;
#pragma unroll
    for (int j = 0; j < 16; j++) {
        float4 f = *(const float4*)(fp + 4 * j);
        float4 p = *(const float4*)(pp + 4 * j);
        lwb16(bufB, 4 * j + 0, t, f.x); lwb16(bufA, 4 * j + 0, t, f.x + p.x);
        lwb16(bufB, 4 * j + 1, t, f.y); lwb16(bufA, 4 * j + 1, t, f.y + p.y);
        lwb16(bufB, 4 * j + 2, t, f.z); lwb16(bufA, 4 * j + 2, t, f.z + p.z);
        lwb16(bufB, 4 * j + 3, t, f.w); lwb16(bufA, 4 * j + 3, t, f.w + p.w);
    }
    __syncthreads();

    const __bf16* Wf_zc   = (const __bf16*)WTf + 0 * 65536;
    const __bf16* Wf_f2w1 = (const __bf16*)WTf + 1 * 65536;

    f32x4 acc[16];
    size_t base = ((size_t)b * HW + pix0) * Cc;

    run_gemm4(bufA, Wf_zc, l15, lhi, lane, w, n0, acc);
#pragma unroll
    for (int nt = 0; nt < 4; nt++)
#pragma unroll
        for (int mt = 0; mt < 4; mt++)
#pragma unroll
            for (int i = 0; i < 4; i++)
                y1[base + (size_t)(mt * 16 + lhi * 4 + i) * Cc + n0 + nt * 16 + l15] =
                    __hip_fp8_e4m3(acc[mt * 4 + nt][i]);

    run_gemm4(bufB, Wf_f2w1, l15, lhi, lane, w, n0, acc);
#pragma unroll
    for (int nt = 0; nt < 4; nt++)
#pragma unroll
        for (int mt = 0; mt < 4; mt++)
#pragma unroll
            for (int i = 0; i < 4; i++)
                y2[base + (size_t)(mt * 16 + lhi * 4 + i) * Cc + n0 + nt * 16 + l15] =
                    __float2bfloat16(acc[mt * 4 + nt][i]);
}

// ---------------------------------------------------------------------------
// 8-wave-half MFMA GEMM core: wave (wm,wn) -> rows [wm*32,+32) x cols [wn*64,+64)
// ---------------------------------------------------------------------------
__device__ __forceinline__ void run_gemm8(const char* __restrict__ Abuf,
                                          const __bf16* __restrict__ Wf,
                                          const float* __restrict__ bias,
                                          int l15, int lhi, int lane, int wm, int wn, f32x4* acc)
{
#pragma unroll
    for (int nt = 0; nt < 4; nt++) {
        float bv = bias ? bias[wn * 64 + nt * 16 + l15] : 0.f;
        f32x4 v = {bv, bv, bv, bv};
        acc[0 * 4 + nt] = v; acc[1 * 4 + nt] = v;
    }
#pragma unroll
    for (int ks = 0; ks < 8; ks++) {
        bf16x8 bfr[4], afr[2];
#pragma unroll
        for (int nt = 0; nt < 4; nt++)
            bfr[nt] = *(const bf16x8*)(Wf + ((((wn * 4 + nt) * 8 + ks) * 64) + lane) * 8);
#pragma unroll
        for (int mt = 0; mt < 2; mt++) {
            int row = wm * 32 + mt * 16 + l15;
            int byte = (row * 512 + (ks * 32 + lhi * 8) * 2) ^ ((row & 7) << 4);
            afr[mt] = *(const bf16x8*)(Abuf + byte);
        }
        __builtin_amdgcn_s_setprio(1);
#pragma unroll
        for (int mt = 0; mt < 2; mt++)
#pragma unroll
            for (int nt = 0; nt < 4; nt++)
                acc[mt * 4 + nt] = __builtin_amdgcn_mfma_f32_16x16x32_bf16(
                    afr[mt], bfr[nt], acc[mt * 4 + nt], 0, 0, 0);
        __builtin_amdgcn_s_setprio(0);
    }
}

// 8-wave-half LN stats. Joint barrier (both halves call in lockstep).
__device__ __forceinline__ void ln_stats8(const f32x4* acc, int l15, int lhi, int wm, int wn,
                                          int tl, float* sred, float* smv)
{
    __syncthreads();
    float s[8], qq[8];
#pragma unroll
    for (int mt = 0; mt < 2; mt++)
#pragma unroll
        for (int i = 0; i < 4; i++) {
            float a = acc[mt * 4 + 0][i], b = acc[mt * 4 + 1][i];
            float c = acc[mt * 4 + 2][i], d = acc[mt * 4 + 3][i];
            s[mt * 4 + i]  = a + b + c + d;
            qq[mt * 4 + i] = a * a + b * b + c * c + d * d;
        }
#pragma unroll
    for (int off = 1; off < 16; off <<= 1)
#pragma unroll
        for (int j = 0; j < 8; j++) {
            s[j]  += __shfl_xor(s[j],  off);
            qq[j] += __shfl_xor(qq[j], off);
        }
    if (l15 == 0) {
#pragma unroll
        for (int mt = 0; mt < 2; mt++)
#pragma unroll
            for (int i = 0; i < 4; i++) {
                int row = wm * 32 + mt * 16 + lhi * 4 + i;
                sred[(row * 4 + wn) * 2]     = s[mt * 4 + i];
                sred[(row * 4 + wn) * 2 + 1] = qq[mt * 4 + i];
            }
    }
    __syncthreads();
    if (tl < 64) {
        float ts = sred[(tl * 4 + 0) * 2] + sred[(tl * 4 + 1) * 2]
                 + sred[(tl * 4 + 2) * 2] + sred[(tl * 4 + 3) * 2];
        float tq = sred[(tl * 4 + 0) * 2 + 1] + sred[(tl * 4 + 1) * 2 + 1]
                 + sred[(tl * 4 + 2) * 2 + 1] + sred[(tl * 4 + 3) * 2 + 1];
        float m = ts * (1.f / 256.f);
        float var = fmaxf(tq * (1.f / 256.f) - m * m, 0.f);
        smv[tl * 2]     = m;
        smv[tl * 2 + 1] = rsqrtf(var + 1e-5f);
    }
    __syncthreads();
}

__device__ __forceinline__ void gate_apply8(const f32x4* acc, const float* __restrict__ g,
                                            const float* __restrict__ bet, const float* smv,
                                            int l15, int lhi, int wm, int wn, unsigned* gp)
{
#pragma unroll
    for (int nt = 0; nt < 4; nt++) {
        int col = wn * 64 + nt * 16 + l15;
        float gg = g[col], gb = bet[col];
#pragma unroll
        for (int mt = 0; mt < 2; mt++) {
            float gv[4];
#pragma unroll
            for (int i = 0; i < 4; i++) {
                int row = wm * 32 + mt * 16 + lhi * 4 + i;
                float u = (acc[mt * 4 + nt][i] - smv[row * 2]) * smv[row * 2 + 1] * gg + gb;
                gv[i] = 1.f / (1.f + __expf(-u));
            }
            gp[(mt * 4 + nt) * 2]     = pk2(gv[0], gv[1]);
            gp[(mt * 4 + nt) * 2 + 1] = pk2(gv[2], gv[3]);
        }
    }
}

// ---------------------------------------------------------------------------
// fused: 1024 threads = 2 independent 512-thread halves, each running the
// proven R15 7-phase pipeline on its OWN query + own 64KB LDS slice.
// One block/CU carries 16 waves (50% occupancy) by construction -> latency
// hiding no longer depends on 2-block co-residency. grid 400, dyn LDS 128KB.
// Both halves execute identical barrier sequences (joint __syncthreads safe).
// ---------------------------------------------------------------------------
__global__ __launch_bounds__(1024, 1) void fused_kernel(
    const float* __restrict__ bboxes,
    const __hip_bfloat16* __restrict__ qk1, const __hip_bfloat16* __restrict__ qf1,
    const __hip_bfloat16* __restrict__ geW1, const __hip_bfloat16* __restrict__ gef1,
    const __hip_fp8_e4m3* __restrict__ y1, const __hip_bfloat16* __restrict__ y2,
    const __hip_bfloat16* __restrict__ WTf,
    const float* __restrict__ bzW2l, const float* __restrict__ b2l,
    const float* __restrict__ f2_b1, const float* __restrict__ f2_b2,
    const float* __restrict__ g1_b1, const float* __restrict__ g1_b2,
    const float* __restrict__ g1_g,  const float* __restrict__ g1_beta,
    const float* __restrict__ g2_b1, const float* __restrict__ g2_b2,
    const float* __restrict__ g2_g,  const float* __restrict__ g2_beta,
    const float* __restrict__ f1_b2,
    const float* __restrict__ out_b, const float* __restrict__ out_g,
    const float* __restrict__ out_beta,
    float* __restrict__ out)
{
    extern __shared__ char smem[];
    const int t = threadIdx.x;
    const int half = t >> 9;          // 0 or 1
    const int tl = t & 511;           // thread id within half
    char*  bufA = smem + half * 65536;          // [64][256] bf16 swizzled
    char*  bufB = bufA + 32768;
    float* stg  = (float*)(smem + half * 65536); // epilogue staging (aliases)

    __shared__ int   ti[2][G49][4];
    __shared__ float tw[2][G49][4];
    __shared__ float tsw[2][G49];
    __shared__ float sred[2][64 * 4 * 2];
    __shared__ float smv[2][64 * 2];

    const int lane = t & 63;
    const int w = tl >> 6;                 // 0..7 within half
    const int wm = w >> 2, wn = w & 3;
    const int l15 = lane & 15, lhi = lane >> 4;
    const int b = blockIdx.x & 7;
    const int qid = b * NQ + ((blockIdx.x >> 3) * 2) + half;   // grid 400

    const __bf16* Wf_g2w1 = (const __bf16*)WTf + 2 * 65536;
    const __bf16* Wf_g2w2 = (const __bf16*)WTf + 3 * 65536;
    const __bf16* Wf_f2w2 = (const __bf16*)WTf + 4 * 65536;
    const __bf16* Wf_g1w1 = (const __bf16*)WTf + 5 * 65536;
    const __bf16* Wf_g1w2 = (const __bf16*)WTf + 6 * 65536;
    const __bf16* Wf_f1w2 = (const __bf16*)WTf + 7 * 65536;
    const __bf16* Wf_outw = (const __bf16*)WTf + 8 * 65536;

    // --- bilinear tap setup (per half) ---
    if (tl < G49) {
        float bb0 = bboxes[qid * 4 + 0];
        float bb1 = bboxes[qid * 4 + 1];
        float bb2 = bboxes[qid * 4 + 2];
        float bb3 = bboxes[qid * 4 + 3];
        int s1 = tl / 7, s2 = tl % 7;
        float ys = bb2 * (1.f / 7.f) * ((float)s1 + 0.5f) + bb1 - 0.5f * bb2;
        float xs = bb3 * (1.f / 7.f) * ((float)s2 + 0.5f) + bb0 - 0.5f * bb3;
        float gx = fminf(fmaxf(2.f * xs - 1.f, -1.f), 1.f);
        float gy = fminf(fmaxf(2.f * ys - 1.f, -1.f), 1.f);
        float ix = ((gx + 1.f) * 64.f - 1.f) * 0.5f;
        float iy = ((gy + 1.f) * 64.f - 1.f) * 0.5f;
        float x0f = floorf(ix), y0f = floorf(iy);
        float wx1 = ix - x0f, wx0 = 1.f - wx1;
        float wy1 = iy - y0f, wy0 = 1.f - wy1;
        int x0 = (int)x0f, y0 = (int)y0f;
        int x1 = x0 + 1, y1i = y0 + 1;
        bool vx0 = (x0 >= 0) & (x0 < 64), vx1 = (x1 >= 0) & (x1 < 64);
        bool vy0 = (y0 >= 0) & (y0 < 64), vy1 = (y1i >= 0) & (y1i < 64);
        int cx0 = min(max(x0, 0), 63), cx1 = min(max(x1, 0), 63);
        int cy0 = min(max(y0, 0), 63), cy1 = min(max(y1i, 0), 63);
        float w0 = (vx0 && vy0) ? wx0 * wy0 : 0.f;
        float w1 = (vx1 && vy0) ? wx1 * wy0 : 0.f;
        float w2 = (vx0 && vy1) ? wx0 * wy1 : 0.f;
        float w3 = (vx1 && vy1) ? wx1 * wy1 : 0.f;
        ti[half][tl][0] = cy0 * 64 + cx0; tw[half][tl][0] = w0;
        ti[half][tl][1] = cy0 * 64 + cx1; tw[half][tl][1] = w1;
        ti[half][tl][2] = cy1 * 64 + cx0; tw[half][tl][2] = w2;
        ti[half][tl][3] = cy1 * 64 + cx1; tw[half][tl][3] = w3;
        tsw[half][tl] = w0 + w1 + w2 + w3;
    }
    if (tl < Cc) {
        for (int r = G49; r < 64; r++) { lwb16(bufA, r, tl, 0.f); lwb16(bufB, r, tl, 0.f); }
    }
    __syncthreads();

    // --- pair-vectorized sampling: y1 -> k (bufB) ; y2 -> relu(+f2_b1) (bufA) ---
    {
        const __hip_fp8_e4m3* y1b = y1 + (size_t)b * HW * Cc;
        const __hip_bfloat16* y2b = y2 + (size_t)b * HW * Cc;
        const int c2 = (tl & 127) * 2;
        const int rs = tl >> 7;           // 0..3
        const float qk0  = ldbf(&qk1[qid * Cc + c2]);
        const float qk1v = ldbf(&qk1[qid * Cc + c2 + 1]);
        const float bzw0 = bzW2l[c2],  bzw1 = bzW2l[c2 + 1];
        const float b20  = b2l[c2],    b21  = b2l[c2 + 1];
        const float fb0  = f2_b1[c2],  fb1  = f2_b1[c2 + 1];
        for (int it = 0; it < 13; it++) {
            int r = it * 4 + rs;
            if (r < G49) {
                int4   tix = *(const int4*)&ti[half][r][0];
                float4 twx = *(const float4*)&tw[half][r][0];
                size_t o0 = (size_t)tix.x * Cc + c2;
                size_t o1 = (size_t)tix.y * Cc + c2;
                size_t o2 = (size_t)tix.z * Cc + c2;
                size_t o3 = (size_t)tix.w * Cc + c2;
                unsigned p0 = *(const unsigned short*)((const char*)y1b + o0);
                unsigned p1 = *(const unsigned short*)((const char*)y1b + o1);
                unsigned p2 = *(const unsigned short*)((const char*)y1b + o2);
                unsigned p3 = *(const unsigned short*)((const char*)y1b + o3);
                unsigned q0 = *(const unsigned*)(y2b + o0);
                unsigned q1 = *(const unsigned*)(y2b + o1);
                unsigned q2 = *(const unsigned*)(y2b + o2);
                unsigned q3 = *(const unsigned*)(y2b + o3);
                float a10 = fp8lo(p0) * twx.x + fp8lo(p1) * twx.y
                          + fp8lo(p2) * twx.z + fp8lo(p3) * twx.w;
                float a11 = fp8hi(p0) * twx.x + fp8hi(p1) * twx.y
                          + fp8hi(p2) * twx.z + fp8hi(p3) * twx.w;
                float a20 = upk(q0, 0) * twx.x + upk(q1, 0) * twx.y
                          + upk(q2, 0) * twx.z + upk(q3, 0) * twx.w;
                float a21 = upk(q0, 1) * twx.x + upk(q1, 1) * twx.y
                          + upk(q2, 1) * twx.z + upk(q3, 1) * twx.w;
                float ts_ = tsw[half][r];
                unsigned gep = *(const unsigned*)(geW1 + r * Cc + c2);
                float kv0 = (qk0  + upk(gep, 0)) * (a10 + ts_ * bzw0 + b20);
                float kv1 = (qk1v + upk(gep, 1)) * (a11 + ts_ * bzw1 + b21);
                int byteB = (r * 512 + c2 * 2) ^ ((r & 7) << 4);
                *(unsigned*)(bufB + byteB) = pk2(kv0, kv1);
                *(unsigned*)(bufA + byteB) = pk2(fmaxf(a20 + fb0, 0.f), fmaxf(a21 + fb1, 0.f));
            }
        }
    }
    __syncthreads();

    f32x4 acc[8], acc2[8];

    // --- G3: m2 = bufA @ f2_w2 + f2_b2 (packed regs) ---
    run_gemm8(bufA, Wf_f2w2, f2_b2, l15, lhi, lane, wm, wn, acc);
    unsigned m2p[16];
#pragma unroll
    for (int j = 0; j < 8; j++) {
        m2p[j * 2]     = pk2(acc[j][0], acc[j][1]);
        m2p[j * 2 + 1] = pk2(acc[j][2], acc[j][3]);
    }

    // --- G4+G7 merged: acc = k@g2w1, acc2 = k@g1w1 ---
    run_gemm8(bufB, Wf_g2w1, g2_b1, l15, lhi, lane, wm, wn, acc);
    run_gemm8(bufB, Wf_g1w1, g1_b1, l15, lhi, lane, wm, wn, acc2);
    __syncthreads();   // fences G3's bufA reads and all k (bufB) reads
#pragma unroll
    for (int nt = 0; nt < 4; nt++)
#pragma unroll
        for (int mt = 0; mt < 2; mt++)
#pragma unroll
            for (int i = 0; i < 4; i++) {
                int row = wm * 32 + mt * 16 + lhi * 4 + i, col = wn * 64 + nt * 16 + l15;
                lwb16(bufA, row, col, fmaxf(acc [mt * 4 + nt][i], 0.f));
                lwb16(bufB, row, col, fmaxf(acc2[mt * 4 + nt][i], 0.f));
            }
    __syncthreads();

    // --- G5: bufA @ g2_w2 ; LN ; gate2 ; comb = gate2*m2 ---
    run_gemm8(bufA, Wf_g2w2, g2_b2, l15, lhi, lane, wm, wn, acc);
    ln_stats8(acc, l15, lhi, wm, wn, tl, sred[half], smv[half]);
    unsigned g2p[16];
    gate_apply8(acc, g2_g, g2_beta, smv[half], l15, lhi, wm, wn, g2p);
    unsigned comb[16];
#pragma unroll
    for (int j = 0; j < 16; j++)
        comb[j] = pk2(upk(g2p[j], 0) * upk(m2p[j], 0), upk(g2p[j], 1) * upk(m2p[j], 1));

    // --- G8: bufB @ g1_w2 ; LN ; gate1 ---
    run_gemm8(bufB, Wf_g1w2, g1_b2, l15, lhi, lane, wm, wn, acc);
    ln_stats8(acc, l15, lhi, wm, wn, tl, sred[half], smv[half]);
    unsigned g1p[16];
    gate_apply8(acc, g1_g, g1_beta, smv[half], l15, lhi, wm, wn, g1p);

    // --- m1 layer1: relu(qf1[col] + gef1[row][col]) -> bufA ---
    // (bufA's last readers = G5 gemm, fenced by G5's ln_stats barriers)
    {
        int col = tl & 255, rh = tl >> 8;   // rh 0..1
        float qf = ldbf(&qf1[qid * Cc + col]);
        for (int it = 0; it < 32; it++) {
            int r = it * 2 + rh;
            int rr = r < G49 ? r : 0;
            lwb16(bufA, r, col, fmaxf(qf + ldbf(&gef1[rr * Cc + col]), 0.f));
        }
    }
    __syncthreads();

    // --- G6: bufA @ f1_w2 ; final = comb + gate1*m1 -> bufA (in place) ---
    run_gemm8(bufA, Wf_f1w2, f1_b2, l15, lhi, lane, wm, wn, acc);
    __syncthreads();
#pragma unroll
    for (int nt = 0; nt < 4; nt++)
#pragma unroll
        for (int mt = 0; mt < 2; mt++)
#pragma unroll
            for (int i = 0; i < 4; i++) {
                int j = mt * 4 + nt;
                int hw_ = i >> 1, lo = i & 1;
                float f = upk(comb[j * 2 + hw_], lo) + upk(g1p[j * 2 + hw_], lo) * acc[j][i];
                lwb16(bufA, wm * 32 + mt * 16 + lhi * 4 + i, wn * 64 + nt * 16 + l15, f);
            }
    __syncthreads();

    // --- G9: bufA @ out_w ; LN ; stage f32 in LDS ; coalesced store ---
    run_gemm8(bufA, Wf_outw, out_b, l15, lhi, lane, wm, wn, acc);
    ln_stats8(acc, l15, lhi, wm, wn, tl, sred[half], smv[half]);
    // all bufA/bufB readers fenced inside ln_stats8 -> reuse as stg
#pragma unroll
    for (int nt = 0; nt < 4; nt++) {
        int col = wn * 64 + nt * 16 + l15;
        float gg = out_g[col], gb = out_beta[col];
#pragma unroll
        for (int mt = 0; mt < 2; mt++)
#pragma unroll
            for (int i = 0; i < 4; i++) {
                int row = wm * 32 + mt * 16 + lhi * 4 + i;
                if (row < G49)
                    stg[row * Cc + col] =
                        (acc[mt * 4 + nt][i] - smv[half][row * 2]) * smv[half][row * 2 + 1] * gg + gb;
            }
    }
    __syncthreads();
    {
        float* ob = out + (size_t)qid * G49 * Cc;
#pragma unroll
        for (int it = 0; it < 7; it++) {
            int fid = it * 512 + tl;
            int r = fid >> 6, c4 = (fid & 63) * 4;
            if (r < G49) {
                f32x4 v = *(const f32x4*)&stg[r * Cc + c4];
                *(f32x4*)&ob[r * Cc + c4] = v;
            }
        }
    }
}

// ---------------------------------------------------------------------------
extern "C" void kernel_launch(void* const* d_in, const int* in_sizes, int n_in,
                              void* d_out, int out_size, void* d_ws, size_t ws_size,
                              hipStream_t stream)
{
    const float* q       = (const float*)d_in[0];
    const float* qpe     = (const float*)d_in[1];
    const float* feat    = (const float*)d_in[2];
    const float* feat_pe = (const float*)d_in[3];
    const float* bboxes  = (const float*)d_in[4];
    const float* ge      = (const float*)d_in[5];
    const float* Wz      = (const float*)d_in[6];
    const float* Wq      = (const float*)d_in[7];
    const float* W1l     = (const float*)d_in[8];
    const float* W2l     = (const float*)d_in[9];
    const float* g1_w1   = (const float*)d_in[10];
    const float* g1_w2   = (const float*)d_in[11];
    const float* g2_w1   = (const float*)d_in[12];
    const float* g2_w2   = (const float*)d_in[13];
    const float* f1_w1   = (const float*)d_in[14];
    const float* f1_w2   = (const float*)d_in[15];
    const float* f2_w1   = (const float*)d_in[16];
    const float* f2_w2   = (const float*)d_in[17];
    const float* out_w   = (const float*)d_in[18];
    const float* bz      = (const float*)d_in[19];
    const float* bq      = (const float*)d_in[20];
    const float* b1l     = (const float*)d_in[21];
    const float* b2l     = (const float*)d_in[22];
    const float* g1_b1   = (const float*)d_in[23];
    const float* g1_b2   = (const float*)d_in[24];
    const float* g2_b1   = (const float*)d_in[25];
    const float* g2_b2   = (const float*)d_in[26];
    const float* f1_b1   = (const float*)d_in[27];
    const float* f1_b2   = (const float*)d_in[28];
    const float* f2_b1   = (const float*)d_in[29];
    const float* f2_b2   = (const float*)d_in[30];
    const float* out_b   = (const float*)d_in[31];
    const float* g1_beta = (const float*)d_in[32];
    const float* g2_beta = (const float*)d_in[33];
    const float* out_beta= (const float*)d_in[34];
    const float* g1_g    = (const float*)d_in[35];
    const float* g2_g    = (const float*)d_in[36];
    const float* out_g   = (const float*)d_in[37];

    char* ws = (char*)d_ws;
    __hip_bfloat16* qk1   = (__hip_bfloat16*)(ws);                  // 409600
    __hip_bfloat16* qf1   = (__hip_bfloat16*)(ws + 409600);         // 409600
    __hip_bfloat16* geW1  = (__hip_bfloat16*)(ws + 819200);         // 25088
    __hip_bfloat16* gef1  = (__hip_bfloat16*)(ws + 844288);         // 25088
    float*          bzW2l = (float*)(ws + 869376);                  // 1024
    float*          WzcF  = (float*)(ws + 870400);                  // 262144
    __hip_bfloat16* WTf   = (__hip_bfloat16*)(ws + 1132544);        // 1179648
    __hip_fp8_e4m3* y1    = (__hip_fp8_e4m3*)(ws + 2312192);        // 8388608
    __hip_bfloat16* y2    = (__hip_bfloat16*)(ws + 10700800);       // 16777216

    // allow 128KB dynamic LDS for the 2-query fused kernel (host-side, capture-safe)
    static bool attr_set = false;
    if (!attr_set) {
        (void)hipFuncSetAttribute((const void*)fused_kernel,
                                  hipFuncAttributeMaxDynamicSharedMemorySize, 131072);
        attr_set = true;
    }

    prep1_kernel<<<dim3(Bb * NQ + G49), dim3(256), 0, stream>>>(
        q, qpe, ge, Wq, bq, W1l, b1l, f1_w1, f1_b1, qk1, qf1, geW1, gef1);

    wfold_kernel<<<dim3(Cc + 1), dim3(256), 0, stream>>>(Wz, W2l, bz, WzcF, bzW2l);

    wprep_kernel<<<dim3(4, 4, 9), dim3(256), 0, stream>>>(
        WzcF, f2_w1, g2_w1, g2_w2, f2_w2, g1_w1, g1_w2, f1_w2, out_w, WTf);

    projA_kernel<<<dim3(512), dim3(256), 65536, stream>>>(feat, feat_pe, WTf, y1, y2);

    fused_kernel<<<dim3(Bb * NQ / 2), dim3(1024), 131072, stream>>>(
        bboxes, qk1, qf1, geW1, gef1, y1, y2, WTf,
        bzW2l, b2l, f2_b1, f2_b2,
        g1_b1, g1_b2, g1_g, g1_beta,
        g2_b1, g2_b2, g2_g, g2_beta,
        f1_b2, out_b, out_g, out_beta, (float*)d_out);
}

// Round 18
// 310.765 us; speedup vs baseline: 1.0131x; 1.0131x over previous
//
#include <hip/hip_runtime.h>
#include <hip/hip_bf16.h>
#include <hip/hip_fp8.h>

constexpr int Cc  = 256;
constexpr int NQ  = 100;
constexpr int Bb  = 8;
constexpr int HW  = 64 * 64;
constexpr int G49 = 49;

typedef __bf16 bf16x8 __attribute__((ext_vector_type(8)));
typedef float  f32x4  __attribute__((ext_vector_type(4)));

__device__ __forceinline__ float ldbf(const __hip_bfloat16* p) { return __bfloat162float(*p); }

__device__ __forceinline__ unsigned pk2(float a, float b) {
    union { unsigned u; __bf16 h[2]; } x;
    x.h[0] = (__bf16)a; x.h[1] = (__bf16)b;
    return x.u;
}
__device__ __forceinline__ float upk(unsigned u, int k) {
    union { unsigned u2; __bf16 h[2]; } x; x.u2 = u;
    return (float)x.h[k];
}
__device__ __forceinline__ float fp8lo(unsigned v) {
    union { unsigned char c; __hip_fp8_e4m3 f; } u; u.c = (unsigned char)(v & 255);
    return (float)u.f;
}
__device__ __forceinline__ float fp8hi(unsigned v) {
    union { unsigned char c; __hip_fp8_e4m3 f; } u; u.c = (unsigned char)((v >> 8) & 255);
    return (float)u.f;
}

// swizzled bf16 LDS write: buffer [64 rows][256 cols] bf16, row stride 512B,
// byte ^= (row&7)<<4 (T2 swizzle)
__device__ __forceinline__ void lwb16(char* buf, int row, int col, float v) {
    int byte = (row * 512 + col * 2) ^ ((row & 7) << 4);
    *(__bf16*)(buf + byte) = (__bf16)v;
}

// ---------------------------------------------------------------------------
// prep1 (unchanged): qk1, qf1, geW1, gef1
// ---------------------------------------------------------------------------
__global__ void prep1_kernel(const float* __restrict__ q, const float* __restrict__ qpe,
                             const float* __restrict__ ge,
                             const float* __restrict__ Wq, const float* __restrict__ bq,
                             const float* __restrict__ W1l, const float* __restrict__ b1l,
                             const float* __restrict__ f1_w1, const float* __restrict__ f1_b1,
                             __hip_bfloat16* __restrict__ qk1, __hip_bfloat16* __restrict__ qf1,
                             __hip_bfloat16* __restrict__ geW1, __hip_bfloat16* __restrict__ gef1)
{
    __shared__ float s[Cc];
    __shared__ float rq[Cc];
    __shared__ float qqs[Cc];
    const int t = threadIdx.x;
    const int blk = blockIdx.x;
    if (blk < Bb * NQ) {
        float a = q[blk * Cc + t], p = qpe[blk * Cc + t];
        rq[t] = a; s[t] = a + p;
        __syncthreads();
        float acc1 = bq[t], acc2 = f1_b1[t];
        for (int k = 0; k < Cc; k++) {
            acc1 = fmaf(s[k],  Wq[k * Cc + t],    acc1);
            acc2 = fmaf(rq[k], f1_w1[k * Cc + t], acc2);
        }
        qqs[t] = acc1;
        qf1[blk * Cc + t] = __float2bfloat16(acc2);
        __syncthreads();
        float acc3 = b1l[t];
        for (int k = 0; k < Cc; k++) acc3 = fmaf(qqs[k], W1l[k * Cc + t], acc3);
        qk1[blk * Cc + t] = __float2bfloat16(acc3);
    } else {
        int g = blk - Bb * NQ;
        s[t] = ge[g * Cc + t];
        __syncthreads();
        float acc1 = 0.f, acc2 = 0.f;
        for (int k = 0; k < Cc; k++) {
            acc1 = fmaf(s[k], W1l[k * Cc + t],   acc1);
            acc2 = fmaf(s[k], f1_w1[k * Cc + t], acc2);
        }
        geW1[g * Cc + t] = __float2bfloat16(acc1);
        gef1[g * Cc + t] = __float2bfloat16(acc2);
    }
}

// ---------------------------------------------------------------------------
// wfold: W_zc = Wz @ W2l (f32) ; bzW2l = bz @ W2l
// ---------------------------------------------------------------------------
__global__ void wfold_kernel(const float* __restrict__ Wz, const float* __restrict__ W2l,
                             const float* __restrict__ bz,
                             float* __restrict__ Wzc, float* __restrict__ bzW2l)
{
    __shared__ float s[Cc];
    const int t = threadIdx.x;
    const int blk = blockIdx.x;
    if (blk < Cc) {
        s[t] = Wz[blk * Cc + t];
        __syncthreads();
        float a = 0.f;
        for (int d = 0; d < Cc; d++) a = fmaf(s[d], W2l[d * Cc + t], a);
        Wzc[blk * Cc + t] = a;
    } else {
        s[t] = bz[t];
        __syncthreads();
        float a = 0.f;
        for (int d = 0; d < Cc; d++) a = fmaf(s[d], W2l[d * Cc + t], a);
        bzW2l[t] = a;
    }
}

// ---------------------------------------------------------------------------
// wprep: W[k][n] f32 -> fragment-ordered bf16 WTf[m][w][nt][ks][lane][8]
// m: 0=Wzc 1=f2w1 (projA) | 2=g2w1 3=g2w2 4=f2w2 5=g1w1 6=g1w2 7=f1w2 8=outw
// ---------------------------------------------------------------------------
__global__ void wprep_kernel(const float* __restrict__ Wzc,  const float* __restrict__ f2w1,
                             const float* __restrict__ g2w1, const float* __restrict__ g2w2,
                             const float* __restrict__ f2w2, const float* __restrict__ g1w1,
                             const float* __restrict__ g1w2, const float* __restrict__ f1w2,
                             const float* __restrict__ outw,
                             __hip_bfloat16* __restrict__ WTf)
{
    __shared__ float ld[64][65];
    const float* srcs[9] = {Wzc, f2w1, g2w1, g2w2, f2w2, g1w1, g1w2, f1w2, outw};
    const int m  = blockIdx.z;
    const int w  = blockIdx.y;
    const int k0 = blockIdx.x * 64;
    const float* src = srcs[m];
    __hip_bfloat16* dst = WTf + (size_t)m * 65536;
    const int t = threadIdx.x;
    const int n0 = w * 64;
#pragma unroll
    for (int j = 0; j < 16; j++) {
        int idx = j * 256 + t; int r = idx >> 6, c = idx & 63;
        ld[r][c] = src[(size_t)(k0 + r) * Cc + n0 + c];
    }
    __syncthreads();
#pragma unroll
    for (int j = 0; j < 16; j++) {
        int idx = j * 256 + t;
        int e  = idx & 7;
        int l  = (idx >> 3) & 63;
        int kk = (idx >> 9) & 1;
        int nt = idx >> 10;
        int k_loc = kk * 32 + ((l >> 4) & 3) * 8 + e;
        int n_loc = nt * 16 + (l & 15);
        int oofs  = ((w * 4 + nt) * 8 + (k0 >> 5) + kk) * 512 + (idx & 511);
        dst[oofs] = __float2bfloat16(ld[k_loc][n_loc]);
    }
}

// ---------------------------------------------------------------------------
// 4-wave MFMA GEMM core (projA only)
// ---------------------------------------------------------------------------
__device__ __forceinline__ void run_gemm4(const char* __restrict__ Abuf,
                                          const __bf16* __restrict__ Wf,
                                          int l15, int lhi, int lane, int w, int n0, f32x4* acc)
{
#pragma unroll
    for (int j = 0; j < 16; j++) { f32x4 v = {0.f, 0.f, 0.f, 0.f}; acc[j] = v; }
#pragma unroll
    for (int ks = 0; ks < 8; ks++) {
        bf16x8 bfr[4], afr[4];
#pragma unroll
        for (int nt = 0; nt < 4; nt++)
            bfr[nt] = *(const bf16x8*)(Wf + ((((w * 4 + nt) * 8 + ks) * 64) + lane) * 8);
#pragma unroll
        for (int mt = 0; mt < 4; mt++) {
            int row = mt * 16 + l15;
            int byte = (row * 512 + (ks * 32 + lhi * 8) * 2) ^ ((row & 7) << 4);
            afr[mt] = *(const bf16x8*)(Abuf + byte);
        }
#pragma unroll
        for (int mt = 0; mt < 4; mt++)
#pragma unroll
            for (int nt = 0; nt < 4; nt++)
                acc[mt * 4 + nt] = __builtin_amdgcn_mfma_f32_16x16x32_bf16(
                    afr[mt], bfr[nt], acc[mt * 4 + nt], 0, 0, 0);
    }
}

// ---------------------------------------------------------------------------
// projA (unchanged): y1 = (feat+pe)@Wzc (fp8), y2 = feat@f2_w1 (bf16)
// ---------------------------------------------------------------------------
__global__ __launch_bounds__(256, 2) void projA_kernel(
    const float* __restrict__ feat, const float* __restrict__ feat_pe,
    const __hip_bfloat16* __restrict__ WTf,
    __hip_fp8_e4m3* __restrict__ y1, __hip_bfloat16* __restrict__ y2)
{
    extern __shared__ char smem[];
    char* bufA = smem;
    char* bufB = smem + 32768;

    const int t = threadIdx.x;
    const int lane = t & 63;
    const int w = t >> 6;
    const int n0 = w * 64;
    const int l15 = lane & 15, lhi = lane >> 4;
    const int b = blockIdx.x >> 6;
    const int pix0 = (blockIdx.x & 63) * 64;

    const float* fp = feat    + ((size_t)(b * Cc + t)) * HW + pix0;
    const float* pp = feat_pe + ((size_t)(b * Cc + t)) * HW + pix0;
#pragma unroll
    for (int j = 0; j < 16; j++) {
        float4 f = *(const float4*)(fp + 4 * j);
        float4 p = *(const float4*)(pp + 4 * j);
        lwb16(bufB, 4 * j + 0, t, f.x); lwb16(bufA, 4 * j + 0, t, f.x + p.x);
        lwb16(bufB, 4 * j + 1, t, f.y); lwb16(bufA, 4 * j + 1, t, f.y + p.y);
        lwb16(bufB, 4 * j + 2, t, f.z); lwb16(bufA, 4 * j + 2, t, f.z + p.z);
        lwb16(bufB, 4 * j + 3, t, f.w); lwb16(bufA, 4 * j + 3, t, f.w + p.w);
    }
    __syncthreads();

    const __bf16* Wf_zc   = (const __bf16*)WTf + 0 * 65536;
    const __bf16* Wf_f2w1 = (const __bf16*)WTf + 1 * 65536;

    f32x4 acc[16];
    size_t base = ((size_t)b * HW + pix0) * Cc;

    run_gemm4(bufA, Wf_zc, l15, lhi, lane, w, n0, acc);
#pragma unroll
    for (int nt = 0; nt < 4; nt++)
#pragma unroll
        for (int mt = 0; mt < 4; mt++)
#pragma unroll
            for (int i = 0; i < 4; i++)
                y1[base + (size_t)(mt * 16 + lhi * 4 + i) * Cc + n0 + nt * 16 + l15] =
                    __hip_fp8_e4m3(acc[mt * 4 + nt][i]);

    run_gemm4(bufB, Wf_f2w1, l15, lhi, lane, w, n0, acc);
#pragma unroll
    for (int nt = 0; nt < 4; nt++)
#pragma unroll
        for (int mt = 0; mt < 4; mt++)
#pragma unroll
            for (int i = 0; i < 4; i++)
                y2[base + (size_t)(mt * 16 + lhi * 4 + i) * Cc + n0 + nt * 16 + l15] =
                    __float2bfloat16(acc[mt * 4 + nt][i]);
}

// ---------------------------------------------------------------------------
// 8-wave-half MFMA GEMM core: wave (wm,wn) -> rows [wm*32,+32) x cols [wn*64,+64)
// ---------------------------------------------------------------------------
__device__ __forceinline__ void run_gemm8(const char* __restrict__ Abuf,
                                          const __bf16* __restrict__ Wf,
                                          const float* __restrict__ bias,
                                          int l15, int lhi, int lane, int wm, int wn, f32x4* acc)
{
#pragma unroll
    for (int nt = 0; nt < 4; nt++) {
        float bv = bias ? bias[wn * 64 + nt * 16 + l15] : 0.f;
        f32x4 v = {bv, bv, bv, bv};
        acc[0 * 4 + nt] = v; acc[1 * 4 + nt] = v;
    }
#pragma unroll
    for (int ks = 0; ks < 8; ks++) {
        bf16x8 bfr[4], afr[2];
#pragma unroll
        for (int nt = 0; nt < 4; nt++)
            bfr[nt] = *(const bf16x8*)(Wf + ((((wn * 4 + nt) * 8 + ks) * 64) + lane) * 8);
#pragma unroll
        for (int mt = 0; mt < 2; mt++) {
            int row = wm * 32 + mt * 16 + l15;
            int byte = (row * 512 + (ks * 32 + lhi * 8) * 2) ^ ((row & 7) << 4);
            afr[mt] = *(const bf16x8*)(Abuf + byte);
        }
        __builtin_amdgcn_s_setprio(1);
#pragma unroll
        for (int mt = 0; mt < 2; mt++)
#pragma unroll
            for (int nt = 0; nt < 4; nt++)
                acc[mt * 4 + nt] = __builtin_amdgcn_mfma_f32_16x16x32_bf16(
                    afr[mt], bfr[nt], acc[mt * 4 + nt], 0, 0, 0);
        __builtin_amdgcn_s_setprio(0);
    }
}

// 8-wave-half LN stats. Joint barrier (both halves call in lockstep).
__device__ __forceinline__ void ln_stats8(const f32x4* acc, int l15, int lhi, int wm, int wn,
                                          int tl, float* sred, float* smv)
{
    __syncthreads();
    float s[8], qq[8];
#pragma unroll
    for (int mt = 0; mt < 2; mt++)
#pragma unroll
        for (int i = 0; i < 4; i++) {
            float a = acc[mt * 4 + 0][i], b = acc[mt * 4 + 1][i];
            float c = acc[mt * 4 + 2][i], d = acc[mt * 4 + 3][i];
            s[mt * 4 + i]  = a + b + c + d;
            qq[mt * 4 + i] = a * a + b * b + c * c + d * d;
        }
#pragma unroll
    for (int off = 1; off < 16; off <<= 1)
#pragma unroll
        for (int j = 0; j < 8; j++) {
            s[j]  += __shfl_xor(s[j],  off);
            qq[j] += __shfl_xor(qq[j], off);
        }
    if (l15 == 0) {
#pragma unroll
        for (int mt = 0; mt < 2; mt++)
#pragma unroll
            for (int i = 0; i < 4; i++) {
                int row = wm * 32 + mt * 16 + lhi * 4 + i;
                sred[(row * 4 + wn) * 2]     = s[mt * 4 + i];
                sred[(row * 4 + wn) * 2 + 1] = qq[mt * 4 + i];
            }
    }
    __syncthreads();
    if (tl < 64) {
        float ts = sred[(tl * 4 + 0) * 2] + sred[(tl * 4 + 1) * 2]
                 + sred[(tl * 4 + 2) * 2] + sred[(tl * 4 + 3) * 2];
        float tq = sred[(tl * 4 + 0) * 2 + 1] + sred[(tl * 4 + 1) * 2 + 1]
                 + sred[(tl * 4 + 2) * 2 + 1] + sred[(tl * 4 + 3) * 2 + 1];
        float m = ts * (1.f / 256.f);
        float var = fmaxf(tq * (1.f / 256.f) - m * m, 0.f);
        smv[tl * 2]     = m;
        smv[tl * 2 + 1] = rsqrtf(var + 1e-5f);
    }
    __syncthreads();
}

__device__ __forceinline__ void gate_apply8(const f32x4* acc, const float* __restrict__ g,
                                            const float* __restrict__ bet, const float* smv,
                                            int l15, int lhi, int wm, int wn, unsigned* gp)
{
#pragma unroll
    for (int nt = 0; nt < 4; nt++) {
        int col = wn * 64 + nt * 16 + l15;
        float gg = g[col], gb = bet[col];
#pragma unroll
        for (int mt = 0; mt < 2; mt++) {
            float gv[4];
#pragma unroll
            for (int i = 0; i < 4; i++) {
                int row = wm * 32 + mt * 16 + lhi * 4 + i;
                float u = (acc[mt * 4 + nt][i] - smv[row * 2]) * smv[row * 2 + 1] * gg + gb;
                gv[i] = 1.f / (1.f + __expf(-u));
            }
            gp[(mt * 4 + nt) * 2]     = pk2(gv[0], gv[1]);
            gp[(mt * 4 + nt) * 2 + 1] = pk2(gv[2], gv[3]);
        }
    }
}

// ---------------------------------------------------------------------------
// fused: 1024 threads = 2 independent 512-thread halves (R17 structure)
// + amdgpu_waves_per_eu(4,4): pin allocator to exactly 4 waves/SIMD ->
// 128-reg budget (known spill-free for this per-wave code at 124 regs),
// instead of the 64-reg squeeze the (1024,1) heuristic chose (R17's spills).
// grid 400, dyn LDS 128KB, 16 waves/CU by construction.
// ---------------------------------------------------------------------------
__global__ __launch_bounds__(1024) __attribute__((amdgpu_waves_per_eu(4, 4)))
void fused_kernel(
    const float* __restrict__ bboxes,
    const __hip_bfloat16* __restrict__ qk1, const __hip_bfloat16* __restrict__ qf1,
    const __hip_bfloat16* __restrict__ geW1, const __hip_bfloat16* __restrict__ gef1,
    const __hip_fp8_e4m3* __restrict__ y1, const __hip_bfloat16* __restrict__ y2,
    const __hip_bfloat16* __restrict__ WTf,
    const float* __restrict__ bzW2l, const float* __restrict__ b2l,
    const float* __restrict__ f2_b1, const float* __restrict__ f2_b2,
    const float* __restrict__ g1_b1, const float* __restrict__ g1_b2,
    const float* __restrict__ g1_g,  const float* __restrict__ g1_beta,
    const float* __restrict__ g2_b1, const float* __restrict__ g2_b2,
    const float* __restrict__ g2_g,  const float* __restrict__ g2_beta,
    const float* __restrict__ f1_b2,
    const float* __restrict__ out_b, const float* __restrict__ out_g,
    const float* __restrict__ out_beta,
    float* __restrict__ out)
{
    extern __shared__ char smem[];
    const int t = threadIdx.x;
    const int half = t >> 9;          // 0 or 1
    const int tl = t & 511;           // thread id within half
    char*  bufA = smem + half * 65536;          // [64][256] bf16 swizzled
    char*  bufB = bufA + 32768;
    float* stg  = (float*)(smem + half * 65536); // epilogue staging (aliases)

    __shared__ int   ti[2][G49][4];
    __shared__ float tw[2][G49][4];
    __shared__ float tsw[2][G49];
    __shared__ float sred[2][64 * 4 * 2];
    __shared__ float smv[2][64 * 2];

    const int lane = t & 63;
    const int w = tl >> 6;                 // 0..7 within half
    const int wm = w >> 2, wn = w & 3;
    const int l15 = lane & 15, lhi = lane >> 4;
    const int b = blockIdx.x & 7;
    const int qid = b * NQ + ((blockIdx.x >> 3) * 2) + half;   // grid 400

    const __bf16* Wf_g2w1 = (const __bf16*)WTf + 2 * 65536;
    const __bf16* Wf_g2w2 = (const __bf16*)WTf + 3 * 65536;
    const __bf16* Wf_f2w2 = (const __bf16*)WTf + 4 * 65536;
    const __bf16* Wf_g1w1 = (const __bf16*)WTf + 5 * 65536;
    const __bf16* Wf_g1w2 = (const __bf16*)WTf + 6 * 65536;
    const __bf16* Wf_f1w2 = (const __bf16*)WTf + 7 * 65536;
    const __bf16* Wf_outw = (const __bf16*)WTf + 8 * 65536;

    // --- bilinear tap setup (per half) ---
    if (tl < G49) {
        float bb0 = bboxes[qid * 4 + 0];
        float bb1 = bboxes[qid * 4 + 1];
        float bb2 = bboxes[qid * 4 + 2];
        float bb3 = bboxes[qid * 4 + 3];
        int s1 = tl / 7, s2 = tl % 7;
        float ys = bb2 * (1.f / 7.f) * ((float)s1 + 0.5f) + bb1 - 0.5f * bb2;
        float xs = bb3 * (1.f / 7.f) * ((float)s2 + 0.5f) + bb0 - 0.5f * bb3;
        float gx = fminf(fmaxf(2.f * xs - 1.f, -1.f), 1.f);
        float gy = fminf(fmaxf(2.f * ys - 1.f, -1.f), 1.f);
        float ix = ((gx + 1.f) * 64.f - 1.f) * 0.5f;
        float iy = ((gy + 1.f) * 64.f - 1.f) * 0.5f;
        float x0f = floorf(ix), y0f = floorf(iy);
        float wx1 = ix - x0f, wx0 = 1.f - wx1;
        float wy1 = iy - y0f, wy0 = 1.f - wy1;
        int x0 = (int)x0f, y0 = (int)y0f;
        int x1 = x0 + 1, y1i = y0 + 1;
        bool vx0 = (x0 >= 0) & (x0 < 64), vx1 = (x1 >= 0) & (x1 < 64);
        bool vy0 = (y0 >= 0) & (y0 < 64), vy1 = (y1i >= 0) & (y1i < 64);
        int cx0 = min(max(x0, 0), 63), cx1 = min(max(x1, 0), 63);
        int cy0 = min(max(y0, 0), 63), cy1 = min(max(y1i, 0), 63);
        float w0 = (vx0 && vy0) ? wx0 * wy0 : 0.f;
        float w1 = (vx1 && vy0) ? wx1 * wy0 : 0.f;
        float w2 = (vx0 && vy1) ? wx0 * wy1 : 0.f;
        float w3 = (vx1 && vy1) ? wx1 * wy1 : 0.f;
        ti[half][tl][0] = cy0 * 64 + cx0; tw[half][tl][0] = w0;
        ti[half][tl][1] = cy0 * 64 + cx1; tw[half][tl][1] = w1;
        ti[half][tl][2] = cy1 * 64 + cx0; tw[half][tl][2] = w2;
        ti[half][tl][3] = cy1 * 64 + cx1; tw[half][tl][3] = w3;
        tsw[half][tl] = w0 + w1 + w2 + w3;
    }
    if (tl < Cc) {
        for (int r = G49; r < 64; r++) { lwb16(bufA, r, tl, 0.f); lwb16(bufB, r, tl, 0.f); }
    }
    __syncthreads();

    // --- pair-vectorized sampling: y1 -> k (bufB) ; y2 -> relu(+f2_b1) (bufA) ---
    {
        const __hip_fp8_e4m3* y1b = y1 + (size_t)b * HW * Cc;
        const __hip_bfloat16* y2b = y2 + (size_t)b * HW * Cc;
        const int c2 = (tl & 127) * 2;
        const int rs = tl >> 7;           // 0..3
        const float qk0  = ldbf(&qk1[qid * Cc + c2]);
        const float qk1v = ldbf(&qk1[qid * Cc + c2 + 1]);
        const float bzw0 = bzW2l[c2],  bzw1 = bzW2l[c2 + 1];
        const float b20  = b2l[c2],    b21  = b2l[c2 + 1];
        const float fb0  = f2_b1[c2],  fb1  = f2_b1[c2 + 1];
        for (int it = 0; it < 13; it++) {
            int r = it * 4 + rs;
            if (r < G49) {
                int4   tix = *(const int4*)&ti[half][r][0];
                float4 twx = *(const float4*)&tw[half][r][0];
                size_t o0 = (size_t)tix.x * Cc + c2;
                size_t o1 = (size_t)tix.y * Cc + c2;
                size_t o2 = (size_t)tix.z * Cc + c2;
                size_t o3 = (size_t)tix.w * Cc + c2;
                unsigned p0 = *(const unsigned short*)((const char*)y1b + o0);
                unsigned p1 = *(const unsigned short*)((const char*)y1b + o1);
                unsigned p2 = *(const unsigned short*)((const char*)y1b + o2);
                unsigned p3 = *(const unsigned short*)((const char*)y1b + o3);
                unsigned q0 = *(const unsigned*)(y2b + o0);
                unsigned q1 = *(const unsigned*)(y2b + o1);
                unsigned q2 = *(const unsigned*)(y2b + o2);
                unsigned q3 = *(const unsigned*)(y2b + o3);
                float a10 = fp8lo(p0) * twx.x + fp8lo(p1) * twx.y
                          + fp8lo(p2) * twx.z + fp8lo(p3) * twx.w;
                float a11 = fp8hi(p0) * twx.x + fp8hi(p1) * twx.y
                          + fp8hi(p2) * twx.z + fp8hi(p3) * twx.w;
                float a20 = upk(q0, 0) * twx.x + upk(q1, 0) * twx.y
                          + upk(q2, 0) * twx.z + upk(q3, 0) * twx.w;
                float a21 = upk(q0, 1) * twx.x + upk(q1, 1) * twx.y
                          + upk(q2, 1) * twx.z + upk(q3, 1) * twx.w;
                float ts_ = tsw[half][r];
                unsigned gep = *(const unsigned*)(geW1 + r * Cc + c2);
                float kv0 = (qk0  + upk(gep, 0)) * (a10 + ts_ * bzw0 + b20);
                float kv1 = (qk1v + upk(gep, 1)) * (a11 + ts_ * bzw1 + b21);
                int byteB = (r * 512 + c2 * 2) ^ ((r & 7) << 4);
                *(unsigned*)(bufB + byteB) = pk2(kv0, kv1);
                *(unsigned*)(bufA + byteB) = pk2(fmaxf(a20 + fb0, 0.f), fmaxf(a21 + fb1, 0.f));
            }
        }
    }
    __syncthreads();

    f32x4 acc[8], acc2[8];

    // --- G3: m2 = bufA @ f2_w2 + f2_b2 (packed regs) ---
    run_gemm8(bufA, Wf_f2w2, f2_b2, l15, lhi, lane, wm, wn, acc);
    unsigned m2p[16];
#pragma unroll
    for (int j = 0; j < 8; j++) {
        m2p[j * 2]     = pk2(acc[j][0], acc[j][1]);
        m2p[j * 2 + 1] = pk2(acc[j][2], acc[j][3]);
    }

    // --- G4+G7 merged: acc = k@g2w1, acc2 = k@g1w1 ---
    run_gemm8(bufB, Wf_g2w1, g2_b1, l15, lhi, lane, wm, wn, acc);
    run_gemm8(bufB, Wf_g1w1, g1_b1, l15, lhi, lane, wm, wn, acc2);
    __syncthreads();   // fences G3's bufA reads and all k (bufB) reads
#pragma unroll
    for (int nt = 0; nt < 4; nt++)
#pragma unroll
        for (int mt = 0; mt < 2; mt++)
#pragma unroll
            for (int i = 0; i < 4; i++) {
                int row = wm * 32 + mt * 16 + lhi * 4 + i, col = wn * 64 + nt * 16 + l15;
                lwb16(bufA, row, col, fmaxf(acc [mt * 4 + nt][i], 0.f));
                lwb16(bufB, row, col, fmaxf(acc2[mt * 4 + nt][i], 0.f));
            }
    __syncthreads();

    // --- G5: bufA @ g2_w2 ; LN ; gate2 ; comb = gate2*m2 ---
    run_gemm8(bufA, Wf_g2w2, g2_b2, l15, lhi, lane, wm, wn, acc);
    ln_stats8(acc, l15, lhi, wm, wn, tl, sred[half], smv[half]);
    unsigned g2p[16];
    gate_apply8(acc, g2_g, g2_beta, smv[half], l15, lhi, wm, wn, g2p);
    unsigned comb[16];
#pragma unroll
    for (int j = 0; j < 16; j++)
        comb[j] = pk2(upk(g2p[j], 0) * upk(m2p[j], 0), upk(g2p[j], 1) * upk(m2p[j], 1));

    // --- G8: bufB @ g1_w2 ; LN ; gate1 ---
    run_gemm8(bufB, Wf_g1w2, g1_b2, l15, lhi, lane, wm, wn, acc);
    ln_stats8(acc, l15, lhi, wm, wn, tl, sred[half], smv[half]);
    unsigned g1p[16];
    gate_apply8(acc, g1_g, g1_beta, smv[half], l15, lhi, wm, wn, g1p);

    // --- m1 layer1: relu(qf1[col] + gef1[row][col]) -> bufA ---
    {
        int col = tl & 255, rh = tl >> 8;   // rh 0..1
        float qf = ldbf(&qf1[qid * Cc + col]);
        for (int it = 0; it < 32; it++) {
            int r = it * 2 + rh;
            int rr = r < G49 ? r : 0;
            lwb16(bufA, r, col, fmaxf(qf + ldbf(&gef1[rr * Cc + col]), 0.f));
        }
    }
    __syncthreads();

    // --- G6: bufA @ f1_w2 ; final = comb + gate1*m1 -> bufA (in place) ---
    run_gemm8(bufA, Wf_f1w2, f1_b2, l15, lhi, lane, wm, wn, acc);
    __syncthreads();
#pragma unroll
    for (int nt = 0; nt < 4; nt++)
#pragma unroll
        for (int mt = 0; mt < 2; mt++)
#pragma unroll
            for (int i = 0; i < 4; i++) {
                int j = mt * 4 + nt;
                int hw_ = i >> 1, lo = i & 1;
                float f = upk(comb[j * 2 + hw_], lo) + upk(g1p[j * 2 + hw_], lo) * acc[j][i];
                lwb16(bufA, wm * 32 + mt * 16 + lhi * 4 + i, wn * 64 + nt * 16 + l15, f);
            }
    __syncthreads();

    // --- G9: bufA @ out_w ; LN ; stage f32 in LDS ; coalesced store ---
    run_gemm8(bufA, Wf_outw, out_b, l15, lhi, lane, wm, wn, acc);
    ln_stats8(acc, l15, lhi, wm, wn, tl, sred[half], smv[half]);
#pragma unroll
    for (int nt = 0; nt < 4; nt++) {
        int col = wn * 64 + nt * 16 + l15;
        float gg = out_g[col], gb = out_beta[col];
#pragma unroll
        for (int mt = 0; mt < 2; mt++)
#pragma unroll
            for (int i = 0; i < 4; i++) {
                int row = wm * 32 + mt * 16 + lhi * 4 + i;
                if (row < G49)
                    stg[row * Cc + col] =
                        (acc[mt * 4 + nt][i] - smv[half][row * 2]) * smv[half][row * 2 + 1] * gg + gb;
            }
    }
    __syncthreads();
    {
        float* ob = out + (size_t)qid * G49 * Cc;
#pragma unroll
        for (int it = 0; it < 7; it++) {
            int fid = it * 512 + tl;
            int r = fid >> 6, c4 = (fid & 63) * 4;
            if (r < G49) {
                f32x4 v = *(const f32x4*)&stg[r * Cc + c4];
                *(f32x4*)&ob[r * Cc + c4] = v;
            }
        }
    }
}

// ---------------------------------------------------------------------------
extern "C" void kernel_launch(void* const* d_in, const int* in_sizes, int n_in,
                              void* d_out, int out_size, void* d_ws, size_t ws_size,
                              hipStream_t stream)
{
    const float* q       = (const float*)d_in[0];
    const float* qpe     = (const float*)d_in[1];
    const float* feat    = (const float*)d_in[2];
    const float* feat_pe = (const float*)d_in[3];
    const float* bboxes  = (const float*)d_in[4];
    const float* ge      = (const float*)d_in[5];
    const float* Wz      = (const float*)d_in[6];
    const float* Wq      = (const float*)d_in[7];
    const float* W1l     = (const float*)d_in[8];
    const float* W2l     = (const float*)d_in[9];
    const float* g1_w1   = (const float*)d_in[10];
    const float* g1_w2   = (const float*)d_in[11];
    const float* g2_w1   = (const float*)d_in[12];
    const float* g2_w2   = (const float*)d_in[13];
    const float* f1_w1   = (const float*)d_in[14];
    const float* f1_w2   = (const float*)d_in[15];
    const float* f2_w1   = (const float*)d_in[16];
    const float* f2_w2   = (const float*)d_in[17];
    const float* out_w   = (const float*)d_in[18];
    const float* bz      = (const float*)d_in[19];
    const float* bq      = (const float*)d_in[20];
    const float* b1l     = (const float*)d_in[21];
    const float* b2l     = (const float*)d_in[22];
    const float* g1_b1   = (const float*)d_in[23];
    const float* g1_b2   = (const float*)d_in[24];
    const float* g2_b1   = (const float*)d_in[25];
    const float* g2_b2   = (const float*)d_in[26];
    const float* f1_b1   = (const float*)d_in[27];
    const float* f1_b2   = (const float*)d_in[28];
    const float* f2_b1   = (const float*)d_in[29];
    const float* f2_b2   = (const float*)d_in[30];
    const float* out_b   = (const float*)d_in[31];
    const float* g1_beta = (const float*)d_in[32];
    const float* g2_beta = (const float*)d_in[33];
    const float* out_beta= (const float*)d_in[34];
    const float* g1_g    = (const float*)d_in[35];
    const float* g2_g    = (const float*)d_in[36];
    const float* out_g   = (const float*)d_in[37];

    char* ws = (char*)d_ws;
    __hip_bfloat16* qk1   = (__hip_bfloat16*)(ws);                  // 409600
    __hip_bfloat16* qf1   = (__hip_bfloat16*)(ws + 409600);         // 409600
    __hip_bfloat16* geW1  = (__hip_bfloat16*)(ws + 819200);         // 25088
    __hip_bfloat16* gef1  = (__hip_bfloat16*)(ws + 844288);         // 25088
    float*          bzW2l = (float*)(ws + 869376);                  // 1024
    float*          WzcF  = (float*)(ws + 870400);                  // 262144
    __hip_bfloat16* WTf   = (__hip_bfloat16*)(ws + 1132544);        // 1179648
    __hip_fp8_e4m3* y1    = (__hip_fp8_e4m3*)(ws + 2312192);        // 8388608
    __hip_bfloat16* y2    = (__hip_bfloat16*)(ws + 10700800);       // 16777216

    static bool attr_set = false;
    if (!attr_set) {
        (void)hipFuncSetAttribute((const void*)fused_kernel,
                                  hipFuncAttributeMaxDynamicSharedMemorySize, 131072);
        attr_set = true;
    }

    prep1_kernel<<<dim3(Bb * NQ + G49), dim3(256), 0, stream>>>(
        q, qpe, ge, Wq, bq, W1l, b1l, f1_w1, f1_b1, qk1, qf1, geW1, gef1);

    wfold_kernel<<<dim3(Cc + 1), dim3(256), 0, stream>>>(Wz, W2l, bz, WzcF, bzW2l);

    wprep_kernel<<<dim3(4, 4, 9), dim3(256), 0, stream>>>(
        WzcF, f2_w1, g2_w1, g2_w2, f2_w2, g1_w1, g1_w2, f1_w2, out_w, WTf);

    projA_kernel<<<dim3(512), dim3(256), 65536, stream>>>(feat, feat_pe, WTf, y1, y2);

    fused_kernel<<<dim3(Bb * NQ / 2), dim3(1024), 131072, stream>>>(
        bboxes, qk1, qf1, geW1, gef1, y1, y2, WTf,
        bzW2l, b2l, f2_b1, f2_b2,
        g1_b1, g1_b2, g1_g, g1_beta,
        g2_b1, g2_b2, g2_g, g2_beta,
        f1_b2, out_b, out_g, out_beta, (float*)d_out);
}

// Round 19
// 257.055 us; speedup vs baseline: 1.2248x; 1.2089x over previous
//
#include <hip/hip_runtime.h>
#include <hip/hip_bf16.h>
#include <hip/hip_fp8.h>

constexpr int Cc  = 256;
constexpr int NQ  = 100;
constexpr int Bb  = 8;
constexpr int HW  = 64 * 64;
constexpr int G49 = 49;

typedef __bf16 bf16x8 __attribute__((ext_vector_type(8)));
typedef float  f32x4  __attribute__((ext_vector_type(4)));

__device__ __forceinline__ float ldbf(const __hip_bfloat16* p) { return __bfloat162float(*p); }

__device__ __forceinline__ unsigned pk2(float a, float b) {
    union { unsigned u; __bf16 h[2]; } x;
    x.h[0] = (__bf16)a; x.h[1] = (__bf16)b;
    return x.u;
}
__device__ __forceinline__ float upk(unsigned u, int k) {
    union { unsigned u2; __bf16 h[2]; } x; x.u2 = u;
    return (float)x.h[k];
}
__device__ __forceinline__ float fp8lo(unsigned v) {
    union { unsigned char c; __hip_fp8_e4m3 f; } u; u.c = (unsigned char)(v & 255);
    return (float)u.f;
}
__device__ __forceinline__ float fp8hi(unsigned v) {
    union { unsigned char c; __hip_fp8_e4m3 f; } u; u.c = (unsigned char)((v >> 8) & 255);
    return (float)u.f;
}

// swizzled bf16 LDS write: buffer [64 rows][256 cols] bf16, row stride 512B,
// byte ^= (row&7)<<4 (T2 swizzle)
__device__ __forceinline__ void lwb16(char* buf, int row, int col, float v) {
    int byte = (row * 512 + col * 2) ^ ((row & 7) << 4);
    *(__bf16*)(buf + byte) = (__bf16)v;
}

// ---------------------------------------------------------------------------
// prep1: qk1, qf1, geW1, gef1
// ---------------------------------------------------------------------------
__global__ void prep1_kernel(const float* __restrict__ q, const float* __restrict__ qpe,
                             const float* __restrict__ ge,
                             const float* __restrict__ Wq, const float* __restrict__ bq,
                             const float* __restrict__ W1l, const float* __restrict__ b1l,
                             const float* __restrict__ f1_w1, const float* __restrict__ f1_b1,
                             __hip_bfloat16* __restrict__ qk1, __hip_bfloat16* __restrict__ qf1,
                             __hip_bfloat16* __restrict__ geW1, __hip_bfloat16* __restrict__ gef1)
{
    __shared__ float s[Cc];
    __shared__ float rq[Cc];
    __shared__ float qqs[Cc];
    const int t = threadIdx.x;
    const int blk = blockIdx.x;
    if (blk < Bb * NQ) {
        float a = q[blk * Cc + t], p = qpe[blk * Cc + t];
        rq[t] = a; s[t] = a + p;
        __syncthreads();
        float acc1 = bq[t], acc2 = f1_b1[t];
        for (int k = 0; k < Cc; k++) {
            acc1 = fmaf(s[k],  Wq[k * Cc + t],    acc1);
            acc2 = fmaf(rq[k], f1_w1[k * Cc + t], acc2);
        }
        qqs[t] = acc1;
        qf1[blk * Cc + t] = __float2bfloat16(acc2);
        __syncthreads();
        float acc3 = b1l[t];
        for (int k = 0; k < Cc; k++) acc3 = fmaf(qqs[k], W1l[k * Cc + t], acc3);
        qk1[blk * Cc + t] = __float2bfloat16(acc3);
    } else {
        int g = blk - Bb * NQ;
        s[t] = ge[g * Cc + t];
        __syncthreads();
        float acc1 = 0.f, acc2 = 0.f;
        for (int k = 0; k < Cc; k++) {
            acc1 = fmaf(s[k], W1l[k * Cc + t],   acc1);
            acc2 = fmaf(s[k], f1_w1[k * Cc + t], acc2);
        }
        geW1[g * Cc + t] = __float2bfloat16(acc1);
        gef1[g * Cc + t] = __float2bfloat16(acc2);
    }
}

// ---------------------------------------------------------------------------
// wfold: W_zc = Wz @ W2l (f32) ; bzW2l = bz @ W2l
// ---------------------------------------------------------------------------
__global__ void wfold_kernel(const float* __restrict__ Wz, const float* __restrict__ W2l,
                             const float* __restrict__ bz,
                             float* __restrict__ Wzc, float* __restrict__ bzW2l)
{
    __shared__ float s[Cc];
    const int t = threadIdx.x;
    const int blk = blockIdx.x;
    if (blk < Cc) {
        s[t] = Wz[blk * Cc + t];
        __syncthreads();
        float a = 0.f;
        for (int d = 0; d < Cc; d++) a = fmaf(s[d], W2l[d * Cc + t], a);
        Wzc[blk * Cc + t] = a;
    } else {
        s[t] = bz[t];
        __syncthreads();
        float a = 0.f;
        for (int d = 0; d < Cc; d++) a = fmaf(s[d], W2l[d * Cc + t], a);
        bzW2l[t] = a;
    }
}

// ---------------------------------------------------------------------------
// wprep: W[k][n] f32 -> fragment-ordered bf16 WTf[m][w][nt][ks][lane][8]
// m: 0=Wzc 1=f2w1 (projA) | 2=g2w1 3=g2w2 4=f2w2 5=g1w1 6=g1w2 7=f1w2 8=outw
// ---------------------------------------------------------------------------
__global__ void wprep_kernel(const float* __restrict__ Wzc,  const float* __restrict__ f2w1,
                             const float* __restrict__ g2w1, const float* __restrict__ g2w2,
                             const float* __restrict__ f2w2, const float* __restrict__ g1w1,
                             const float* __restrict__ g1w2, const float* __restrict__ f1w2,
                             const float* __restrict__ outw,
                             __hip_bfloat16* __restrict__ WTf)
{
    __shared__ float ld[64][65];
    const float* srcs[9] = {Wzc, f2w1, g2w1, g2w2, f2w2, g1w1, g1w2, f1w2, outw};
    const int m  = blockIdx.z;
    const int w  = blockIdx.y;
    const int k0 = blockIdx.x * 64;
    const float* src = srcs[m];
    __hip_bfloat16* dst = WTf + (size_t)m * 65536;
    const int t = threadIdx.x;
    const int n0 = w * 64;
#pragma unroll
    for (int j = 0; j < 16; j++) {
        int idx = j * 256 + t; int r = idx >> 6, c = idx & 63;
        ld[r][c] = src[(size_t)(k0 + r) * Cc + n0 + c];
    }
    __syncthreads();
#pragma unroll
    for (int j = 0; j < 16; j++) {
        int idx = j * 256 + t;
        int e  = idx & 7;
        int l  = (idx >> 3) & 63;
        int kk = (idx >> 9) & 1;
        int nt = idx >> 10;
        int k_loc = kk * 32 + ((l >> 4) & 3) * 8 + e;
        int n_loc = nt * 16 + (l & 15);
        int oofs  = ((w * 4 + nt) * 8 + (k0 >> 5) + kk) * 512 + (idx & 511);
        dst[oofs] = __float2bfloat16(ld[k_loc][n_loc]);
    }
}

// ---------------------------------------------------------------------------
// 4-wave MFMA GEMM core (projA only)
// ---------------------------------------------------------------------------
__device__ __forceinline__ void run_gemm4(const char* __restrict__ Abuf,
                                          const __bf16* __restrict__ Wf,
                                          int l15, int lhi, int lane, int w, int n0, f32x4* acc)
{
#pragma unroll
    for (int j = 0; j < 16; j++) { f32x4 v = {0.f, 0.f, 0.f, 0.f}; acc[j] = v; }
#pragma unroll
    for (int ks = 0; ks < 8; ks++) {
        bf16x8 bfr[4], afr[4];
#pragma unroll
        for (int nt = 0; nt < 4; nt++)
            bfr[nt] = *(const bf16x8*)(Wf + ((((w * 4 + nt) * 8 + ks) * 64) + lane) * 8);
#pragma unroll
        for (int mt = 0; mt < 4; mt++) {
            int row = mt * 16 + l15;
            int byte = (row * 512 + (ks * 32 + lhi * 8) * 2) ^ ((row & 7) << 4);
            afr[mt] = *(const bf16x8*)(Abuf + byte);
        }
#pragma unroll
        for (int mt = 0; mt < 4; mt++)
#pragma unroll
            for (int nt = 0; nt < 4; nt++)
                acc[mt * 4 + nt] = __builtin_amdgcn_mfma_f32_16x16x32_bf16(
                    afr[mt], bfr[nt], acc[mt * 4 + nt], 0, 0, 0);
    }
}

// ---------------------------------------------------------------------------
// projA: y1 = (feat+pe)@Wzc (fp8), y2 = feat@f2_w1 (bf16)
// ---------------------------------------------------------------------------
__global__ __launch_bounds__(256, 2) void projA_kernel(
    const float* __restrict__ feat, const float* __restrict__ feat_pe,
    const __hip_bfloat16* __restrict__ WTf,
    __hip_fp8_e4m3* __restrict__ y1, __hip_bfloat16* __restrict__ y2)
{
    extern __shared__ char smem[];
    char* bufA = smem;
    char* bufB = smem + 32768;

    const int t = threadIdx.x;
    const int lane = t & 63;
    const int w = t >> 6;
    const int n0 = w * 64;
    const int l15 = lane & 15, lhi = lane >> 4;
    const int b = blockIdx.x >> 6;
    const int pix0 = (blockIdx.x & 63) * 64;

    const float* fp = feat    + ((size_t)(b * Cc + t)) * HW + pix0;
    const float* pp = feat_pe + ((size_t)(b * Cc + t)) * HW + pix0;
#pragma unroll
    for (int j = 0; j < 16; j++) {
        float4 f = *(const float4*)(fp + 4 * j);
        float4 p = *(const float4*)(pp + 4 * j);
        lwb16(bufB, 4 * j + 0, t, f.x); lwb16(bufA, 4 * j + 0, t, f.x + p.x);
        lwb16(bufB, 4 * j + 1, t, f.y); lwb16(bufA, 4 * j + 1, t, f.y + p.y);
        lwb16(bufB, 4 * j + 2, t, f.z); lwb16(bufA, 4 * j + 2, t, f.z + p.z);
        lwb16(bufB, 4 * j + 3, t, f.w); lwb16(bufA, 4 * j + 3, t, f.w + p.w);
    }
    __syncthreads();

    const __bf16* Wf_zc   = (const __bf16*)WTf + 0 * 65536;
    const __bf16* Wf_f2w1 = (const __bf16*)WTf + 1 * 65536;

    f32x4 acc[16];
    size_t base = ((size_t)b * HW + pix0) * Cc;

    run_gemm4(bufA, Wf_zc, l15, lhi, lane, w, n0, acc);
#pragma unroll
    for (int nt = 0; nt < 4; nt++)
#pragma unroll
        for (int mt = 0; mt < 4; mt++)
#pragma unroll
            for (int i = 0; i < 4; i++)
                y1[base + (size_t)(mt * 16 + lhi * 4 + i) * Cc + n0 + nt * 16 + l15] =
                    __hip_fp8_e4m3(acc[mt * 4 + nt][i]);

    run_gemm4(bufB, Wf_f2w1, l15, lhi, lane, w, n0, acc);
#pragma unroll
    for (int nt = 0; nt < 4; nt++)
#pragma unroll
        for (int mt = 0; mt < 4; mt++)
#pragma unroll
            for (int i = 0; i < 4; i++)
                y2[base + (size_t)(mt * 16 + lhi * 4 + i) * Cc + n0 + nt * 16 + l15] =
                    __float2bfloat16(acc[mt * 4 + nt][i]);
}

// ---------------------------------------------------------------------------
// 8-wave MFMA GEMM core: wave (wm,wn) -> rows [wm*32,+32) x cols [wn*64,+64)
// ---------------------------------------------------------------------------
__device__ __forceinline__ void run_gemm8(const char* __restrict__ Abuf,
                                          const __bf16* __restrict__ Wf,
                                          const float* __restrict__ bias,
                                          int l15, int lhi, int lane, int wm, int wn, f32x4* acc)
{
#pragma unroll
    for (int nt = 0; nt < 4; nt++) {
        float bv = bias ? bias[wn * 64 + nt * 16 + l15] : 0.f;
        f32x4 v = {bv, bv, bv, bv};
        acc[0 * 4 + nt] = v; acc[1 * 4 + nt] = v;
    }
#pragma unroll
    for (int ks = 0; ks < 8; ks++) {
        bf16x8 bfr[4], afr[2];
#pragma unroll
        for (int nt = 0; nt < 4; nt++)
            bfr[nt] = *(const bf16x8*)(Wf + ((((wn * 4 + nt) * 8 + ks) * 64) + lane) * 8);
#pragma unroll
        for (int mt = 0; mt < 2; mt++) {
            int row = wm * 32 + mt * 16 + l15;
            int byte = (row * 512 + (ks * 32 + lhi * 8) * 2) ^ ((row & 7) << 4);
            afr[mt] = *(const bf16x8*)(Abuf + byte);
        }
        __builtin_amdgcn_s_setprio(1);
#pragma unroll
        for (int mt = 0; mt < 2; mt++)
#pragma unroll
            for (int nt = 0; nt < 4; nt++)
                acc[mt * 4 + nt] = __builtin_amdgcn_mfma_f32_16x16x32_bf16(
                    afr[mt], bfr[nt], acc[mt * 4 + nt], 0, 0, 0);
        __builtin_amdgcn_s_setprio(0);
    }
}

// 8-wave LN stats. Entry barrier fences prior GEMM LDS reads vs sred writes.
__device__ __forceinline__ void ln_stats8(const f32x4* acc, int l15, int lhi, int wm, int wn,
                                          int t, float* sred, float* smv)
{
    __syncthreads();
    float s[8], qq[8];
#pragma unroll
    for (int mt = 0; mt < 2; mt++)
#pragma unroll
        for (int i = 0; i < 4; i++) {
            float a = acc[mt * 4 + 0][i], b = acc[mt * 4 + 1][i];
            float c = acc[mt * 4 + 2][i], d = acc[mt * 4 + 3][i];
            s[mt * 4 + i]  = a + b + c + d;
            qq[mt * 4 + i] = a * a + b * b + c * c + d * d;
        }
#pragma unroll
    for (int off = 1; off < 16; off <<= 1)
#pragma unroll
        for (int j = 0; j < 8; j++) {
            s[j]  += __shfl_xor(s[j],  off);
            qq[j] += __shfl_xor(qq[j], off);
        }
    if (l15 == 0) {
#pragma unroll
        for (int mt = 0; mt < 2; mt++)
#pragma unroll
            for (int i = 0; i < 4; i++) {
                int row = wm * 32 + mt * 16 + lhi * 4 + i;
                sred[(row * 4 + wn) * 2]     = s[mt * 4 + i];
                sred[(row * 4 + wn) * 2 + 1] = qq[mt * 4 + i];
            }
    }
    __syncthreads();
    if (t < 64) {
        float ts = sred[(t * 4 + 0) * 2] + sred[(t * 4 + 1) * 2]
                 + sred[(t * 4 + 2) * 2] + sred[(t * 4 + 3) * 2];
        float tq = sred[(t * 4 + 0) * 2 + 1] + sred[(t * 4 + 1) * 2 + 1]
                 + sred[(t * 4 + 2) * 2 + 1] + sred[(t * 4 + 3) * 2 + 1];
        float m = ts * (1.f / 256.f);
        float var = fmaxf(tq * (1.f / 256.f) - m * m, 0.f);
        smv[t * 2]     = m;
        smv[t * 2 + 1] = rsqrtf(var + 1e-5f);
    }
    __syncthreads();
}

__device__ __forceinline__ void gate_apply8(const f32x4* acc, const float* __restrict__ g,
                                            const float* __restrict__ bet, const float* smv,
                                            int l15, int lhi, int wm, int wn, unsigned* gp)
{
#pragma unroll
    for (int nt = 0; nt < 4; nt++) {
        int col = wn * 64 + nt * 16 + l15;
        float gg = g[col], gb = bet[col];
#pragma unroll
        for (int mt = 0; mt < 2; mt++) {
            float gv[4];
#pragma unroll
            for (int i = 0; i < 4; i++) {
                int row = wm * 32 + mt * 16 + lhi * 4 + i;
                float u = (acc[mt * 4 + nt][i] - smv[row * 2]) * smv[row * 2 + 1] * gg + gb;
                gv[i] = 1.f / (1.f + __expf(-u));
            }
            gp[(mt * 4 + nt) * 2]     = pk2(gv[0], gv[1]);
            gp[(mt * 4 + nt) * 2 + 1] = pk2(gv[2], gv[3]);
        }
    }
}

// ---------------------------------------------------------------------------
// fused: 8-wave (512-thread) 7-phase pipeline. grid 800, dyn LDS 64KB.
// Best-known config (R15/R16): 124 VGPR, zero spill, FETCH ~= compulsory.
// ---------------------------------------------------------------------------
__global__ __launch_bounds__(512, 2) void fused_kernel(
    const float* __restrict__ bboxes,
    const __hip_bfloat16* __restrict__ qk1, const __hip_bfloat16* __restrict__ qf1,
    const __hip_bfloat16* __restrict__ geW1, const __hip_bfloat16* __restrict__ gef1,
    const __hip_fp8_e4m3* __restrict__ y1, const __hip_bfloat16* __restrict__ y2,
    const __hip_bfloat16* __restrict__ WTf,
    const float* __restrict__ bzW2l, const float* __restrict__ b2l,
    const float* __restrict__ f2_b1, const float* __restrict__ f2_b2,
    const float* __restrict__ g1_b1, const float* __restrict__ g1_b2,
    const float* __restrict__ g1_g,  const float* __restrict__ g1_beta,
    const float* __restrict__ g2_b1, const float* __restrict__ g2_b2,
    const float* __restrict__ g2_g,  const float* __restrict__ g2_beta,
    const float* __restrict__ f1_b2,
    const float* __restrict__ out_b, const float* __restrict__ out_g,
    const float* __restrict__ out_beta,
    float* __restrict__ out)
{
    extern __shared__ char smem[];
    char* bufA = smem;            // m2-in -> g2relu -> m1 -> final
    char* bufB = smem + 32768;    // k -> g1relu
    float* stg = (float*)smem;    // G9 epilogue staging (aliases both)

    __shared__ int   ti[G49][4];
    __shared__ float tw[G49][4];
    __shared__ float tsw[G49];
    __shared__ float sred[64 * 4 * 2];
    __shared__ float smv[64 * 2];

    const int t = threadIdx.x;
    const int lane = t & 63;
    const int w = t >> 6;                 // 0..7
    const int wm = w >> 2, wn = w & 3;    // rows [wm*32,+32) x cols [wn*64,+64)
    const int l15 = lane & 15, lhi = lane >> 4;
    const int qid = (blockIdx.x & 7) * NQ + (blockIdx.x >> 3);
    const int b = blockIdx.x & 7;

    const __bf16* Wf_g2w1 = (const __bf16*)WTf + 2 * 65536;
    const __bf16* Wf_g2w2 = (const __bf16*)WTf + 3 * 65536;
    const __bf16* Wf_f2w2 = (const __bf16*)WTf + 4 * 65536;
    const __bf16* Wf_g1w1 = (const __bf16*)WTf + 5 * 65536;
    const __bf16* Wf_g1w2 = (const __bf16*)WTf + 6 * 65536;
    const __bf16* Wf_f1w2 = (const __bf16*)WTf + 7 * 65536;
    const __bf16* Wf_outw = (const __bf16*)WTf + 8 * 65536;

    // --- bilinear tap setup ---
    if (t < G49) {
        float bb0 = bboxes[qid * 4 + 0];
        float bb1 = bboxes[qid * 4 + 1];
        float bb2 = bboxes[qid * 4 + 2];
        float bb3 = bboxes[qid * 4 + 3];
        int s1 = t / 7, s2 = t % 7;
        float ys = bb2 * (1.f / 7.f) * ((float)s1 + 0.5f) + bb1 - 0.5f * bb2;
        float xs = bb3 * (1.f / 7.f) * ((float)s2 + 0.5f) + bb0 - 0.5f * bb3;
        float gx = fminf(fmaxf(2.f * xs - 1.f, -1.f), 1.f);
        float gy = fminf(fmaxf(2.f * ys - 1.f, -1.f), 1.f);
        float ix = ((gx + 1.f) * 64.f - 1.f) * 0.5f;
        float iy = ((gy + 1.f) * 64.f - 1.f) * 0.5f;
        float x0f = floorf(ix), y0f = floorf(iy);
        float wx1 = ix - x0f, wx0 = 1.f - wx1;
        float wy1 = iy - y0f, wy0 = 1.f - wy1;
        int x0 = (int)x0f, y0 = (int)y0f;
        int x1 = x0 + 1, y1i = y0 + 1;
        bool vx0 = (x0 >= 0) & (x0 < 64), vx1 = (x1 >= 0) & (x1 < 64);
        bool vy0 = (y0 >= 0) & (y0 < 64), vy1 = (y1i >= 0) & (y1i < 64);
        int cx0 = min(max(x0, 0), 63), cx1 = min(max(x1, 0), 63);
        int cy0 = min(max(y0, 0), 63), cy1 = min(max(y1i, 0), 63);
        float w0 = (vx0 && vy0) ? wx0 * wy0 : 0.f;
        float w1 = (vx1 && vy0) ? wx1 * wy0 : 0.f;
        float w2 = (vx0 && vy1) ? wx0 * wy1 : 0.f;
        float w3 = (vx1 && vy1) ? wx1 * wy1 : 0.f;
        ti[t][0] = cy0 * 64 + cx0; tw[t][0] = w0;
        ti[t][1] = cy0 * 64 + cx1; tw[t][1] = w1;
        ti[t][2] = cy1 * 64 + cx0; tw[t][2] = w2;
        ti[t][3] = cy1 * 64 + cx1; tw[t][3] = w3;
        tsw[t] = w0 + w1 + w2 + w3;
    }
    if (t < Cc) {
        for (int r = G49; r < 64; r++) { lwb16(bufA, r, t, 0.f); lwb16(bufB, r, t, 0.f); }
    }
    __syncthreads();

    // --- pair-vectorized sampling: y1 -> k (bufB) ; y2 -> relu(+f2_b1) (bufA) ---
    {
        const __hip_fp8_e4m3* y1b = y1 + (size_t)b * HW * Cc;
        const __hip_bfloat16* y2b = y2 + (size_t)b * HW * Cc;
        const int c2 = (t & 127) * 2;
        const int rs = t >> 7;           // 0..3
        const float qk0  = ldbf(&qk1[qid * Cc + c2]);
        const float qk1v = ldbf(&qk1[qid * Cc + c2 + 1]);
        const float bzw0 = bzW2l[c2],  bzw1 = bzW2l[c2 + 1];
        const float b20  = b2l[c2],    b21  = b2l[c2 + 1];
        const float fb0  = f2_b1[c2],  fb1  = f2_b1[c2 + 1];
        for (int it = 0; it < 13; it++) {
            int r = it * 4 + rs;
            if (r < G49) {
                int4   tix = *(const int4*)&ti[r][0];
                float4 twx = *(const float4*)&tw[r][0];
                size_t o0 = (size_t)tix.x * Cc + c2;
                size_t o1 = (size_t)tix.y * Cc + c2;
                size_t o2 = (size_t)tix.z * Cc + c2;
                size_t o3 = (size_t)tix.w * Cc + c2;
                unsigned p0 = *(const unsigned short*)((const char*)y1b + o0);
                unsigned p1 = *(const unsigned short*)((const char*)y1b + o1);
                unsigned p2 = *(const unsigned short*)((const char*)y1b + o2);
                unsigned p3 = *(const unsigned short*)((const char*)y1b + o3);
                unsigned q0 = *(const unsigned*)(y2b + o0);
                unsigned q1 = *(const unsigned*)(y2b + o1);
                unsigned q2 = *(const unsigned*)(y2b + o2);
                unsigned q3 = *(const unsigned*)(y2b + o3);
                float a10 = fp8lo(p0) * twx.x + fp8lo(p1) * twx.y
                          + fp8lo(p2) * twx.z + fp8lo(p3) * twx.w;
                float a11 = fp8hi(p0) * twx.x + fp8hi(p1) * twx.y
                          + fp8hi(p2) * twx.z + fp8hi(p3) * twx.w;
                float a20 = upk(q0, 0) * twx.x + upk(q1, 0) * twx.y
                          + upk(q2, 0) * twx.z + upk(q3, 0) * twx.w;
                float a21 = upk(q0, 1) * twx.x + upk(q1, 1) * twx.y
                          + upk(q2, 1) * twx.z + upk(q3, 1) * twx.w;
                float ts_ = tsw[r];
                unsigned gep = *(const unsigned*)(geW1 + r * Cc + c2);
                float kv0 = (qk0  + upk(gep, 0)) * (a10 + ts_ * bzw0 + b20);
                float kv1 = (qk1v + upk(gep, 1)) * (a11 + ts_ * bzw1 + b21);
                int byteB = (r * 512 + c2 * 2) ^ ((r & 7) << 4);
                *(unsigned*)(bufB + byteB) = pk2(kv0, kv1);
                *(unsigned*)(bufA + byteB) = pk2(fmaxf(a20 + fb0, 0.f), fmaxf(a21 + fb1, 0.f));
            }
        }
    }
    __syncthreads();

    f32x4 acc[8], acc2[8];

    // --- G3: m2 = bufA @ f2_w2 + f2_b2 (packed regs) ---
    run_gemm8(bufA, Wf_f2w2, f2_b2, l15, lhi, lane, wm, wn, acc);
    unsigned m2p[16];
#pragma unroll
    for (int j = 0; j < 8; j++) {
        m2p[j * 2]     = pk2(acc[j][0], acc[j][1]);
        m2p[j * 2 + 1] = pk2(acc[j][2], acc[j][3]);
    }

    // --- G4+G7 merged: acc = k@g2w1, acc2 = k@g1w1 ---
    run_gemm8(bufB, Wf_g2w1, g2_b1, l15, lhi, lane, wm, wn, acc);
    run_gemm8(bufB, Wf_g1w1, g1_b1, l15, lhi, lane, wm, wn, acc2);
    __syncthreads();   // fences G3's bufA reads and all k (bufB) reads
#pragma unroll
    for (int nt = 0; nt < 4; nt++)
#pragma unroll
        for (int mt = 0; mt < 2; mt++)
#pragma unroll
            for (int i = 0; i < 4; i++) {
                int row = wm * 32 + mt * 16 + lhi * 4 + i, col = wn * 64 + nt * 16 + l15;
                lwb16(bufA, row, col, fmaxf(acc [mt * 4 + nt][i], 0.f));
                lwb16(bufB, row, col, fmaxf(acc2[mt * 4 + nt][i], 0.f));
            }
    __syncthreads();

    // --- G5: bufA @ g2_w2 ; LN ; gate2 ; comb = gate2*m2 ---
    run_gemm8(bufA, Wf_g2w2, g2_b2, l15, lhi, lane, wm, wn, acc);
    ln_stats8(acc, l15, lhi, wm, wn, t, sred, smv);
    unsigned g2p[16];
    gate_apply8(acc, g2_g, g2_beta, smv, l15, lhi, wm, wn, g2p);
    unsigned comb[16];
#pragma unroll
    for (int j = 0; j < 16; j++)
        comb[j] = pk2(upk(g2p[j], 0) * upk(m2p[j], 0), upk(g2p[j], 1) * upk(m2p[j], 1));

    // --- G8: bufB @ g1_w2 ; LN ; gate1 ---
    run_gemm8(bufB, Wf_g1w2, g1_b2, l15, lhi, lane, wm, wn, acc);
    ln_stats8(acc, l15, lhi, wm, wn, t, sred, smv);
    unsigned g1p[16];
    gate_apply8(acc, g1_g, g1_beta, smv, l15, lhi, wm, wn, g1p);

    // --- m1 layer1: relu(qf1[col] + gef1[row][col]) -> bufA ---
    // (bufA's last readers = G5 gemm, fenced by G5's ln_stats barriers)
    {
        int col = t & 255, rh = t >> 8;   // rh 0..1
        float qf = ldbf(&qf1[qid * Cc + col]);
        for (int it = 0; it < 32; it++) {
            int r = it * 2 + rh;
            int rr = r < G49 ? r : 0;
            lwb16(bufA, r, col, fmaxf(qf + ldbf(&gef1[rr * Cc + col]), 0.f));
        }
    }
    __syncthreads();

    // --- G6: bufA @ f1_w2 ; final = comb + gate1*m1 -> bufA (in place) ---
    run_gemm8(bufA, Wf_f1w2, f1_b2, l15, lhi, lane, wm, wn, acc);
    __syncthreads();
#pragma unroll
    for (int nt = 0; nt < 4; nt++)
#pragma unroll
        for (int mt = 0; mt < 2; mt++)
#pragma unroll
            for (int i = 0; i < 4; i++) {
                int j = mt * 4 + nt;
                int hw_ = i >> 1, lo = i & 1;
                float f = upk(comb[j * 2 + hw_], lo) + upk(g1p[j * 2 + hw_], lo) * acc[j][i];
                lwb16(bufA, wm * 32 + mt * 16 + lhi * 4 + i, wn * 64 + nt * 16 + l15, f);
            }
    __syncthreads();

    // --- G9: bufA @ out_w ; LN ; stage f32 in LDS ; coalesced store ---
    run_gemm8(bufA, Wf_outw, out_b, l15, lhi, lane, wm, wn, acc);
    ln_stats8(acc, l15, lhi, wm, wn, t, sred, smv);
    // all bufA/bufB readers fenced inside ln_stats8 -> reuse as stg
#pragma unroll
    for (int nt = 0; nt < 4; nt++) {
        int col = wn * 64 + nt * 16 + l15;
        float gg = out_g[col], gb = out_beta[col];
#pragma unroll
        for (int mt = 0; mt < 2; mt++)
#pragma unroll
            for (int i = 0; i < 4; i++) {
                int row = wm * 32 + mt * 16 + lhi * 4 + i;
                if (row < G49)
                    stg[row * Cc + col] =
                        (acc[mt * 4 + nt][i] - smv[row * 2]) * smv[row * 2 + 1] * gg + gb;
            }
    }
    __syncthreads();
    {
        float* ob = out + (size_t)qid * G49 * Cc;
#pragma unroll
        for (int it = 0; it < 7; it++) {
            int fid = it * 512 + t;
            int r = fid >> 6, c4 = (fid & 63) * 4;
            if (r < G49) {
                f32x4 v = *(const f32x4*)&stg[r * Cc + c4];
                *(f32x4*)&ob[r * Cc + c4] = v;
            }
        }
    }
}

// ---------------------------------------------------------------------------
extern "C" void kernel_launch(void* const* d_in, const int* in_sizes, int n_in,
                              void* d_out, int out_size, void* d_ws, size_t ws_size,
                              hipStream_t stream)
{
    const float* q       = (const float*)d_in[0];
    const float* qpe     = (const float*)d_in[1];
    const float* feat    = (const float*)d_in[2];
    const float* feat_pe = (const float*)d_in[3];
    const float* bboxes  = (const float*)d_in[4];
    const float* ge      = (const float*)d_in[5];
    const float* Wz      = (const float*)d_in[6];
    const float* Wq      = (const float*)d_in[7];
    const float* W1l     = (const float*)d_in[8];
    const float* W2l     = (const float*)d_in[9];
    const float* g1_w1   = (const float*)d_in[10];
    const float* g1_w2   = (const float*)d_in[11];
    const float* g2_w1   = (const float*)d_in[12];
    const float* g2_w2   = (const float*)d_in[13];
    const float* f1_w1   = (const float*)d_in[14];
    const float* f1_w2   = (const float*)d_in[15];
    const float* f2_w1   = (const float*)d_in[16];
    const float* f2_w2   = (const float*)d_in[17];
    const float* out_w   = (const float*)d_in[18];
    const float* bz      = (const float*)d_in[19];
    const float* bq      = (const float*)d_in[20];
    const float* b1l     = (const float*)d_in[21];
    const float* b2l     = (const float*)d_in[22];
    const float* g1_b1   = (const float*)d_in[23];
    const float* g1_b2   = (const float*)d_in[24];
    const float* g2_b1   = (const float*)d_in[25];
    const float* g2_b2   = (const float*)d_in[26];
    const float* f1_b1   = (const float*)d_in[27];
    const float* f1_b2   = (const float*)d_in[28];
    const float* f2_b1   = (const float*)d_in[29];
    const float* f2_b2   = (const float*)d_in[30];
    const float* out_b   = (const float*)d_in[31];
    const float* g1_beta = (const float*)d_in[32];
    const float* g2_beta = (const float*)d_in[33];
    const float* out_beta= (const float*)d_in[34];
    const float* g1_g    = (const float*)d_in[35];
    const float* g2_g    = (const float*)d_in[36];
    const float* out_g   = (const float*)d_in[37];

    char* ws = (char*)d_ws;
    __hip_bfloat16* qk1   = (__hip_bfloat16*)(ws);                  // 409600
    __hip_bfloat16* qf1   = (__hip_bfloat16*)(ws + 409600);         // 409600
    __hip_bfloat16* geW1  = (__hip_bfloat16*)(ws + 819200);         // 25088
    __hip_bfloat16* gef1  = (__hip_bfloat16*)(ws + 844288);         // 25088
    float*          bzW2l = (float*)(ws + 869376);                  // 1024
    float*          WzcF  = (float*)(ws + 870400);                  // 262144
    __hip_bfloat16* WTf   = (__hip_bfloat16*)(ws + 1132544);        // 1179648
    __hip_fp8_e4m3* y1    = (__hip_fp8_e4m3*)(ws + 2312192);        // 8388608
    __hip_bfloat16* y2    = (__hip_bfloat16*)(ws + 10700800);       // 16777216

    prep1_kernel<<<dim3(Bb * NQ + G49), dim3(256), 0, stream>>>(
        q, qpe, ge, Wq, bq, W1l, b1l, f1_w1, f1_b1, qk1, qf1, geW1, gef1);

    wfold_kernel<<<dim3(Cc + 1), dim3(256), 0, stream>>>(Wz, W2l, bz, WzcF, bzW2l);

    wprep_kernel<<<dim3(4, 4, 9), dim3(256), 0, stream>>>(
        WzcF, f2_w1, g2_w1, g2_w2, f2_w2, g1_w1, g1_w2, f1_w2, out_w, WTf);

    projA_kernel<<<dim3(512), dim3(256), 65536, stream>>>(feat, feat_pe, WTf, y1, y2);

    fused_kernel<<<dim3(Bb * NQ), dim3(512), 65536, stream>>>(
        bboxes, qk1, qf1, geW1, gef1, y1, y2, WTf,
        bzW2l, b2l, f2_b1, f2_b2,
        g1_b1, g1_b2, g1_g, g1_beta,
        g2_b1, g2_b2, g2_g, g2_beta,
        f1_b2, out_b, out_g, out_beta, (float*)d_out);
}